// Round 1
// baseline (3922.299 us; speedup 1.0000x reference)
//
#include <hip/hip_runtime.h>

#define NN 60000
#define NE 180000
#define NG 2048
#define HD 256
#define NL 5

typedef unsigned short u16;
typedef unsigned int u32;
typedef __bf16 bf16x8 __attribute__((ext_vector_type(8)));
typedef float f32x4 __attribute__((ext_vector_type(4)));

__device__ __forceinline__ u16 f2bf(float f) {
    u32 u = __builtin_bit_cast(u32, f);
    u += 0x7FFFu + ((u >> 16) & 1u);
    return (u16)(u >> 16);
}
__device__ __forceinline__ float bf2f(u16 s) {
    return __builtin_bit_cast(float, (u32)s << 16);
}

__constant__ int NODE_OFF[9]  = {0, 119, 124, 136, 148, 158, 164, 170, 172};
__constant__ int NODE_MAXC[9] = {118, 4, 11, 11, 9, 5, 5, 1, 1};
__constant__ int EDGE_OFF[3]  = {0, 5, 11};
__constant__ int EDGE_MAXC[3] = {4, 5, 1};

// ---- transpose + bf16-cast the 21 256x256 weight matrices ----
__global__ __launch_bounds__(256) void k_prep_weights(
    const float* __restrict__ W1, const float* __restrict__ W2,
    const float* __restrict__ vW1, const float* __restrict__ vW2,
    const float* __restrict__ hW1, u16* __restrict__ Wt)
{
    int mat = blockIdx.x >> 8;
    int n = blockIdx.x & 255;
    int k = threadIdx.x;
    const float* src;
    if (mat < 5)       src = W1 + (size_t)mat * 65536;
    else if (mat < 10) src = W2 + (size_t)(mat - 5) * 65536;
    else if (mat < 15) src = vW1 + (size_t)(mat - 10) * 65536;
    else if (mat < 20) src = vW2 + (size_t)(mat - 15) * 65536;
    else               src = hW1;
    Wt[(size_t)mat * 65536 + n * 256 + k] = f2bf(src[k * 256 + n]);
}

// ---- per-graph segment starts via binary search (batch is sorted) ----
__global__ __launch_bounds__(256) void k_starts(const int* __restrict__ batch,
                                                int* __restrict__ starts)
{
    int g = blockIdx.x * 256 + threadIdx.x;
    if (g > NG) return;
    int lo = 0, hi = NN;
    while (lo < hi) {
        int mid = (lo + hi) >> 1;
        if (batch[mid] < g) lo = mid + 1; else hi = mid;
    }
    starts[g] = lo;
}

__global__ __launch_bounds__(256) void k_vn_init(const float* __restrict__ vn_emb,
                                                 float* __restrict__ vn)
{
    int i = blockIdx.x * 256 + threadIdx.x;
    vn[i] = vn_emb[i & 255];
}

// ---- node embedding: h = sum of 9 table rows ----
__global__ __launch_bounds__(256) void k_embed(const int* __restrict__ x,
                                               const float* __restrict__ node_emb,
                                               float* __restrict__ h)
{
    int i = blockIdx.x * 4 + (threadIdx.x >> 6);
    if (i >= NN) return;
    int c = (threadIdx.x & 63) * 4;
    float4 s = make_float4(0.f, 0.f, 0.f, 0.f);
#pragma unroll
    for (int f = 0; f < 9; ++f) {
        int xv = x[i * 9 + f];
        xv = xv < 0 ? 0 : (xv > NODE_MAXC[f] ? NODE_MAXC[f] : xv);
        const float4 t = *(const float4*)&node_emb[(size_t)(NODE_OFF[f] + xv) * 256 + c];
        s.x += t.x; s.y += t.y; s.z += t.z; s.w += t.w;
    }
    *(float4*)&h[(size_t)i * 256 + c] = s;
}

// ---- edge message + scatter-add:  agg[dst] += relu(h[src]+vn[batch[src]]+ea) ----
__global__ __launch_bounds__(256) void k_scatter(
    const float* __restrict__ h, const float* __restrict__ vn,
    const int* __restrict__ batch, const int* __restrict__ src,
    const int* __restrict__ dst, const int* __restrict__ eattr,
    const float* __restrict__ eemb, float* __restrict__ agg)
{
    int e = blockIdx.x * 4 + (threadIdx.x >> 6);
    if (e >= NE) return;
    int c = (threadIdx.x & 63) * 4;
    int s = src[e], d = dst[e];
    int b = batch[s];
    const float4 hv = *(const float4*)&h[(size_t)s * 256 + c];
    const float4 vv = *(const float4*)&vn[(size_t)b * 256 + c];
    float4 m = make_float4(hv.x + vv.x, hv.y + vv.y, hv.z + vv.z, hv.w + vv.w);
#pragma unroll
    for (int f = 0; f < 3; ++f) {
        int a = eattr[e * 3 + f];
        a = a < 0 ? 0 : (a > EDGE_MAXC[f] ? EDGE_MAXC[f] : a);
        const float4 t = *(const float4*)&eemb[(size_t)(EDGE_OFF[f] + a) * 256 + c];
        m.x += t.x; m.y += t.y; m.z += t.z; m.w += t.w;
    }
    float* p = &agg[(size_t)d * 256 + c];
    atomicAdd(p + 0, fmaxf(m.x, 0.f));
    atomicAdd(p + 1, fmaxf(m.y, 0.f));
    atomicAdd(p + 2, fmaxf(m.z, 0.f));
    atomicAdd(p + 3, fmaxf(m.w, 0.f));
}

// ---- A = bf16((1+eps)*(h+vn[batch]) + agg); agg = 0 for next layer ----
__global__ __launch_bounds__(256) void k_prepA(
    const float* __restrict__ h, const float* __restrict__ vn,
    const int* __restrict__ batch, float* __restrict__ agg,
    u16* __restrict__ Abf, const float* __restrict__ epsp)
{
    size_t i = (size_t)blockIdx.x * 256 + threadIdx.x;  // float4 index
    int row = (int)(i >> 6);
    if (row >= NN) return;
    int b = batch[row];
    int c = ((int)i & 63) * 4;
    float ep = 1.0f + *epsp;
    float4 hv = *(const float4*)&h[i * 4];
    float4 vv = *(const float4*)&vn[(size_t)b * 256 + c];
    float4 av = *(const float4*)&agg[i * 4];
    float4 z;
    z.x = (hv.x + vv.x) * ep + av.x;
    z.y = (hv.y + vv.y) * ep + av.y;
    z.z = (hv.z + vv.z) * ep + av.z;
    z.w = (hv.w + vv.w) * ep + av.w;
    ushort4 o;
    o.x = f2bf(z.x); o.y = f2bf(z.y); o.z = f2bf(z.z); o.w = f2bf(z.w);
    *(ushort4*)&Abf[i * 4] = o;
    *(float4*)&agg[i * 4] = make_float4(0.f, 0.f, 0.f, 0.f);
}

// ---- GEMM: C[M,256] = A[M,256] @ B[256,256], A bf16 row-major, B pre-transposed bf16
// EPI 0: out = bf16(relu(acc+bias))      EPI 1: out = f32(relu(BN(acc+bias)))
// EPI 2: addbuf += acc+bias (vn update)
template <int EPI>
__global__ __launch_bounds__(256) void k_gemm(
    const u16* __restrict__ A, const u16* __restrict__ Bt,
    void* __restrict__ Cout, const float* __restrict__ bias,
    const float* __restrict__ bng, const float* __restrict__ bnb,
    const float* __restrict__ bnm, const float* __restrict__ bnv,
    float* __restrict__ addbuf, int M)
{
    __shared__ __align__(16) u16 Al[128 * 128];
    __shared__ __align__(16) u16 Bl[128 * 128];
    const int bm = blockIdx.x >> 1, bn = blockIdx.x & 1;
    const int m0 = bm * 128, n0 = bn * 128;
    const int tid = threadIdx.x, lane = tid & 63, wid = tid >> 6;
    const int wm = (wid >> 1) * 64, wn = (wid & 1) * 64;
    f32x4 acc[4][4] = {};

    for (int k0 = 0; k0 < 256; k0 += 128) {
        __syncthreads();
#pragma unroll
        for (int it = 0; it < 8; ++it) {
            int cch = it * 256 + tid;
            int row = cch >> 4, col = cch & 15;
            int lofs = ((row << 8) + (col << 4)) ^ ((row & 7) << 4);
            uint4 va = make_uint4(0, 0, 0, 0);
            int grow = m0 + row;
            if (grow < M)
                va = *(const uint4*)((const char*)A + ((size_t)grow * 512 + (size_t)k0 * 2 + (col << 4)));
            *(uint4*)((char*)Al + lofs) = va;
            uint4 vb = *(const uint4*)((const char*)Bt + ((size_t)(n0 + row) * 512 + (size_t)k0 * 2 + (col << 4)));
            *(uint4*)((char*)Bl + lofs) = vb;
        }
        __syncthreads();
#pragma unroll
        for (int kt = 0; kt < 4; ++kt) {
            bf16x8 af[4], bfr[4];
            int kb = kt * 64 + ((lane >> 4) << 4);
#pragma unroll
            for (int t = 0; t < 4; ++t) {
                int ar = wm + t * 16 + (lane & 15);
                af[t] = __builtin_bit_cast(bf16x8,
                    *(const uint4*)((const char*)Al + (((ar << 8) + kb) ^ ((ar & 7) << 4))));
                int br = wn + t * 16 + (lane & 15);
                bfr[t] = __builtin_bit_cast(bf16x8,
                    *(const uint4*)((const char*)Bl + (((br << 8) + kb) ^ ((br & 7) << 4))));
            }
#pragma unroll
            for (int i = 0; i < 4; ++i)
#pragma unroll
                for (int j = 0; j < 4; ++j)
                    acc[i][j] = __builtin_amdgcn_mfma_f32_16x16x32_bf16(af[i], bfr[j], acc[i][j], 0, 0, 0);
        }
    }

    const int cl = lane & 15, rg = lane >> 4;
#pragma unroll
    for (int j = 0; j < 4; ++j) {
        int gn = n0 + wn + j * 16 + cl;
        float bv = bias[gn];
        float sc = 0.f, sh = 0.f;
        if constexpr (EPI == 1) {
            sc = bng[gn] * rsqrtf(bnv[gn] + 1e-5f);
            sh = bnb[gn] - bnm[gn] * sc;
        }
#pragma unroll
        for (int i = 0; i < 4; ++i) {
#pragma unroll
            for (int r = 0; r < 4; ++r) {
                int gm = m0 + wm + i * 16 + rg * 4 + r;
                if (gm >= M) continue;
                float v = acc[i][j][r] + bv;
                if constexpr (EPI == 0) {
                    ((u16*)Cout)[(size_t)gm * 256 + gn] = f2bf(fmaxf(v, 0.f));
                } else if constexpr (EPI == 1) {
                    ((float*)Cout)[(size_t)gm * 256 + gn] = fmaxf(v * sc + sh, 0.f);
                } else {
                    addbuf[(size_t)gm * 256 + gn] += v;
                }
            }
        }
    }
}

// ---- mean pool per graph (sorted batch, contiguous segments) -> bf16 ----
__global__ __launch_bounds__(256) void k_pool(const float* __restrict__ h,
                                              const int* __restrict__ starts,
                                              u16* __restrict__ gbf)
{
    int g = blockIdx.x;
    int c = threadIdx.x;
    int s0 = starts[g], s1 = starts[g + 1];
    float sum = 0.f;
    for (int i = s0; i < s1; ++i) sum += h[(size_t)i * 256 + c];
    float cnt = (float)(s1 - s0);
    gbf[(size_t)g * 256 + c] = f2bf(sum / fmaxf(cnt, 1.0f));
}

// ---- head matvec: logits[m] = dot(Th[m,:], hW2) + hb2 ----
__global__ __launch_bounds__(256) void k_head(const u16* __restrict__ Th,
                                              const float* __restrict__ hW2,
                                              const float* __restrict__ hb2,
                                              float* __restrict__ out)
{
    int m = blockIdx.x * 4 + (threadIdx.x >> 6);
    int lane = threadIdx.x & 63;
    const ushort4 t = *(const ushort4*)&Th[(size_t)m * 256 + lane * 4];
    float s = bf2f(t.x) * hW2[lane * 4 + 0] + bf2f(t.y) * hW2[lane * 4 + 1] +
              bf2f(t.z) * hW2[lane * 4 + 2] + bf2f(t.w) * hW2[lane * 4 + 3];
#pragma unroll
    for (int o = 32; o > 0; o >>= 1) s += __shfl_down(s, o);
    if (lane == 0) out[m] = s + hb2[0];
}

extern "C" void kernel_launch(void* const* d_in, const int* in_sizes, int n_in,
                              void* d_out, int out_size, void* d_ws, size_t ws_size,
                              hipStream_t stream)
{
    const int*   x        = (const int*)d_in[0];
    const int*   ei       = (const int*)d_in[1];
    const int*   eattr    = (const int*)d_in[2];
    const int*   batch    = (const int*)d_in[3];
    const float* node_emb = (const float*)d_in[4];
    const float* edge_emb = (const float*)d_in[5];
    const float* vn_emb   = (const float*)d_in[6];
    const float* eps      = (const float*)d_in[7];
    const float* W1       = (const float*)d_in[8];
    const float* b1       = (const float*)d_in[9];
    const float* W2       = (const float*)d_in[10];
    const float* b2       = (const float*)d_in[11];
    const float* bng      = (const float*)d_in[12];
    const float* bnb      = (const float*)d_in[13];
    const float* bnm      = (const float*)d_in[14];
    const float* bnv      = (const float*)d_in[15];
    const float* vW1      = (const float*)d_in[16];
    const float* vb1      = (const float*)d_in[17];
    const float* vW2      = (const float*)d_in[18];
    const float* vb2      = (const float*)d_in[19];
    const float* hW1      = (const float*)d_in[20];
    const float* hb1      = (const float*)d_in[21];
    const float* hW2      = (const float*)d_in[22];
    const float* hb2      = (const float*)d_in[23];
    float* out = (float*)d_out;

    char* ws = (char*)d_ws;
    size_t off = 0;
    auto alloc = [&](size_t b) {
        char* p = ws + off;
        off = (off + b + 255) & ~(size_t)255;
        return p;
    };
    float* h    = (float*)alloc((size_t)NN * 256 * 4);
    float* agg  = (float*)alloc((size_t)NN * 256 * 4);
    u16*   Abf  = (u16*)alloc((size_t)NN * 256 * 2);
    u16*   T    = (u16*)alloc((size_t)NN * 256 * 2);
    float* vn   = (float*)alloc((size_t)NG * 256 * 4);
    u16*   gbf  = (u16*)alloc((size_t)NG * 256 * 2);
    u16*   Tg   = (u16*)alloc((size_t)NG * 256 * 2);
    u16*   Wt   = (u16*)alloc((size_t)21 * 65536 * 2);
    int*   starts = (int*)alloc((size_t)(NG + 1) * 4);

    const int* srcI = ei;
    const int* dstI = ei + NE;

    k_prep_weights<<<21 * 256, 256, 0, stream>>>(W1, W2, vW1, vW2, hW1, Wt);
    k_starts<<<(NG + 1 + 255) / 256, 256, 0, stream>>>(batch, starts);
    k_vn_init<<<NG, 256, 0, stream>>>(vn_emb, vn);
    k_embed<<<NN / 4, 256, 0, stream>>>(x, node_emb, h);
    hipMemsetAsync(agg, 0, (size_t)NN * 256 * 4, stream);

    const int GBIG = ((NN + 127) / 128) * 2;  // 938 blocks
    const int GSMALL = (NG / 128) * 2;        // 32 blocks

    for (int l = 0; l < NL; ++l) {
        k_scatter<<<NE / 4, 256, 0, stream>>>(h, vn, batch, srcI, dstI, eattr, edge_emb, agg);
        k_prepA<<<NN * 64 / 256, 256, 0, stream>>>(h, vn, batch, agg, Abf, eps + l);
        k_gemm<0><<<GBIG, 256, 0, stream>>>(Abf, Wt + (size_t)(0 + l) * 65536, T,
                                            b1 + l * 256, nullptr, nullptr, nullptr, nullptr,
                                            nullptr, NN);
        k_gemm<1><<<GBIG, 256, 0, stream>>>(T, Wt + (size_t)(5 + l) * 65536, h,
                                            b2 + l * 256, bng + l * 256, bnb + l * 256,
                                            bnm + l * 256, bnv + l * 256, nullptr, NN);
        k_pool<<<NG, 256, 0, stream>>>(h, starts, gbf);
        k_gemm<0><<<GSMALL, 256, 0, stream>>>(gbf, Wt + (size_t)(10 + l) * 65536, Tg,
                                              vb1 + l * 256, nullptr, nullptr, nullptr, nullptr,
                                              nullptr, NG);
        k_gemm<2><<<GSMALL, 256, 0, stream>>>(Tg, Wt + (size_t)(15 + l) * 65536, nullptr,
                                              vb2 + l * 256, nullptr, nullptr, nullptr, nullptr,
                                              vn, NG);
    }
    k_pool<<<NG, 256, 0, stream>>>(h, starts, gbf);
    k_gemm<0><<<GSMALL, 256, 0, stream>>>(gbf, Wt + (size_t)20 * 65536, Tg,
                                          hb1, nullptr, nullptr, nullptr, nullptr,
                                          nullptr, NG);
    k_head<<<NG / 4, 256, 0, stream>>>(Tg, hW2, hb2, out);
}

// Round 2
// 995.817 us; speedup vs baseline: 3.9388x; 3.9388x over previous
//
#include <hip/hip_runtime.h>

#define NN 60000
#define NE 180000
#define NG 2048
#define HD 256
#define NL 5
#define CAP 32

typedef unsigned short u16;
typedef unsigned int u32;
typedef __bf16 bf16x8 __attribute__((ext_vector_type(8)));
typedef float f32x4 __attribute__((ext_vector_type(4)));

__device__ __forceinline__ u16 f2bf(float f) {
    u32 u = __builtin_bit_cast(u32, f);
    u += 0x7FFFu + ((u >> 16) & 1u);
    return (u16)(u >> 16);
}
__device__ __forceinline__ float bf2f(u16 s) {
    return __builtin_bit_cast(float, (u32)s << 16);
}

__constant__ int NODE_OFF[9]  = {0, 119, 124, 136, 148, 158, 164, 170, 172};
__constant__ int NODE_MAXC[9] = {118, 4, 11, 11, 9, 5, 5, 1, 1};

// ---- transpose + bf16-cast the 21 256x256 weight matrices ----
__global__ __launch_bounds__(256) void k_prep_weights(
    const float* __restrict__ W1, const float* __restrict__ W2,
    const float* __restrict__ vW1, const float* __restrict__ vW2,
    const float* __restrict__ hW1, u16* __restrict__ Wt)
{
    int mat = blockIdx.x >> 8;
    int n = blockIdx.x & 255;
    int k = threadIdx.x;
    const float* src;
    if (mat < 5)       src = W1 + (size_t)mat * 65536;
    else if (mat < 10) src = W2 + (size_t)(mat - 5) * 65536;
    else if (mat < 15) src = vW1 + (size_t)(mat - 10) * 65536;
    else if (mat < 20) src = vW2 + (size_t)(mat - 15) * 65536;
    else               src = hW1;
    Wt[(size_t)mat * 65536 + n * 256 + k] = f2bf(src[k * 256 + n]);
}

// ---- combined edge-attr embedding table: 60 rows (5*6*2) x 256 ----
__global__ __launch_bounds__(256) void k_comb(const float* __restrict__ eemb,
                                              float* __restrict__ comb)
{
    int r = blockIdx.x;
    int c = threadIdx.x;
    int a0 = r / 12, a1 = (r % 12) / 2, a2 = r & 1;
    comb[r * 256 + c] = eemb[(0 + a0) * 256 + c] + eemb[(5 + a1) * 256 + c] +
                        eemb[(11 + a2) * 256 + c];
}

// ---- per-graph segment starts via binary search (batch is sorted) ----
__global__ __launch_bounds__(256) void k_starts(const int* __restrict__ batch,
                                                int* __restrict__ starts)
{
    int g = blockIdx.x * 256 + threadIdx.x;
    if (g > NG) return;
    int lo = 0, hi = NN;
    while (lo < hi) {
        int mid = (lo + hi) >> 1;
        if (batch[mid] < g) lo = mid + 1; else hi = mid;
    }
    starts[g] = lo;
}

__global__ __launch_bounds__(256) void k_vn_init(const float* __restrict__ vn_emb,
                                                 float* __restrict__ vn)
{
    int i = blockIdx.x * 256 + threadIdx.x;
    vn[i] = vn_emb[i & 255];
}

// ---- node embedding: h = sum of 9 table rows ----
__global__ __launch_bounds__(256) void k_embed(const int* __restrict__ x,
                                               const float* __restrict__ node_emb,
                                               float* __restrict__ h)
{
    int i = blockIdx.x * 4 + (threadIdx.x >> 6);
    if (i >= NN) return;
    int c = (threadIdx.x & 63) * 4;
    float4 s = make_float4(0.f, 0.f, 0.f, 0.f);
#pragma unroll
    for (int f = 0; f < 9; ++f) {
        int xv = x[i * 9 + f];
        xv = xv < 0 ? 0 : (xv > NODE_MAXC[f] ? NODE_MAXC[f] : xv);
        const float4 t = *(const float4*)&node_emb[(size_t)(NODE_OFF[f] + xv) * 256 + c];
        s.x += t.x; s.y += t.y; s.z += t.z; s.w += t.w;
    }
    *(float4*)&h[(size_t)i * 256 + c] = s;
}

// ---- CSR-bucket build: slots[d*CAP+p] = src | code<<17 ----
__global__ __launch_bounds__(256) void k_bucket(
    const int* __restrict__ src, const int* __restrict__ dst,
    const int* __restrict__ eattr, int* __restrict__ deg, u32* __restrict__ slots)
{
    int e = blockIdx.x * 256 + threadIdx.x;
    if (e >= NE) return;
    int a0 = eattr[e * 3 + 0]; a0 = a0 < 0 ? 0 : (a0 > 4 ? 4 : a0);
    int a1 = eattr[e * 3 + 1]; a1 = a1 < 0 ? 0 : (a1 > 5 ? 5 : a1);
    int a2 = eattr[e * 3 + 2]; a2 = a2 < 0 ? 0 : (a2 > 1 ? 1 : a2);
    u32 code = (u32)(a0 * 12 + a1 * 2 + a2);
    int d = dst[e];
    int p = atomicAdd(&deg[d], 1);
    if (p < CAP) slots[(size_t)d * CAP + p] = (u32)src[e] | (code << 17);
}

// ---- fused aggregation + A-prep:
//   acc = sum_e relu(h[src]+vn[batch[src]]+comb[code])
//   A[d] = bf16((1+eps)*(h[d]+vn[batch[d]]) + acc)
__global__ __launch_bounds__(256) void k_agg(
    const float* __restrict__ h, const float* __restrict__ vn,
    const int* __restrict__ batch, const u32* __restrict__ slots,
    const int* __restrict__ deg, const float* __restrict__ comb,
    u16* __restrict__ Abf, const float* __restrict__ epsp)
{
    int d = blockIdx.x * 4 + (threadIdx.x >> 6);
    int lane = threadIdx.x & 63;
    int c = lane * 4;
    int nd = deg[d];
    nd = nd > CAP ? CAP : nd;

    // lane-parallel prefetch of slot words + batch ids, broadcast via shfl
    const u32* sl = slots + (size_t)d * CAP;
    u32 sv_l = (lane < nd) ? sl[lane] : 0u;
    int b_l = (lane < nd) ? batch[sv_l & 0x1FFFFu] : 0;

    float4 acc = make_float4(0.f, 0.f, 0.f, 0.f);
    for (int p = 0; p < nd; ++p) {
        u32 sv = (u32)__shfl((int)sv_l, p);
        int b  = __shfl(b_l, p);
        int s  = (int)(sv & 0x1FFFFu);
        int code = (int)(sv >> 17);
        const float4 hv = *(const float4*)&h[(size_t)s * 256 + c];
        const float4 vv = *(const float4*)&vn[(size_t)b * 256 + c];
        const float4 tv = *(const float4*)&comb[(size_t)code * 256 + c];
        acc.x += fmaxf(hv.x + vv.x + tv.x, 0.f);
        acc.y += fmaxf(hv.y + vv.y + tv.y, 0.f);
        acc.z += fmaxf(hv.z + vv.z + tv.z, 0.f);
        acc.w += fmaxf(hv.w + vv.w + tv.w, 0.f);
    }

    int bd = batch[d];
    float ep = 1.0f + *epsp;
    const float4 hd = *(const float4*)&h[(size_t)d * 256 + c];
    const float4 vd = *(const float4*)&vn[(size_t)bd * 256 + c];
    ushort4 o;
    o.x = f2bf((hd.x + vd.x) * ep + acc.x);
    o.y = f2bf((hd.y + vd.y) * ep + acc.y);
    o.z = f2bf((hd.z + vd.z) * ep + acc.z);
    o.w = f2bf((hd.w + vd.w) * ep + acc.w);
    *(ushort4*)&Abf[(size_t)d * 256 + c] = o;
}

// ---- GEMM: C[M,256] = A[M,256] @ B[256,256], A bf16 row-major, B pre-transposed bf16
// EPI 0: out = bf16(relu(acc+bias))      EPI 1: out = f32(relu(BN(acc+bias)))
// EPI 2: addbuf += acc+bias (vn update)
template <int EPI>
__global__ __launch_bounds__(256) void k_gemm(
    const u16* __restrict__ A, const u16* __restrict__ Bt,
    void* __restrict__ Cout, const float* __restrict__ bias,
    const float* __restrict__ bng, const float* __restrict__ bnb,
    const float* __restrict__ bnm, const float* __restrict__ bnv,
    float* __restrict__ addbuf, int M)
{
    __shared__ __align__(16) u16 Al[128 * 128];
    __shared__ __align__(16) u16 Bl[128 * 128];
    const int bm = blockIdx.x >> 1, bn = blockIdx.x & 1;
    const int m0 = bm * 128, n0 = bn * 128;
    const int tid = threadIdx.x, lane = tid & 63, wid = tid >> 6;
    const int wm = (wid >> 1) * 64, wn = (wid & 1) * 64;
    f32x4 acc[4][4] = {};

    for (int k0 = 0; k0 < 256; k0 += 128) {
        __syncthreads();
#pragma unroll
        for (int it = 0; it < 8; ++it) {
            int cch = it * 256 + tid;
            int row = cch >> 4, col = cch & 15;
            int lofs = ((row << 8) + (col << 4)) ^ ((row & 7) << 4);
            uint4 va = make_uint4(0, 0, 0, 0);
            int grow = m0 + row;
            if (grow < M)
                va = *(const uint4*)((const char*)A + ((size_t)grow * 512 + (size_t)k0 * 2 + (col << 4)));
            *(uint4*)((char*)Al + lofs) = va;
            uint4 vb = *(const uint4*)((const char*)Bt + ((size_t)(n0 + row) * 512 + (size_t)k0 * 2 + (col << 4)));
            *(uint4*)((char*)Bl + lofs) = vb;
        }
        __syncthreads();
#pragma unroll
        for (int kt = 0; kt < 4; ++kt) {
            bf16x8 af[4], bfr[4];
            int kb = kt * 64 + ((lane >> 4) << 4);
#pragma unroll
            for (int t = 0; t < 4; ++t) {
                int ar = wm + t * 16 + (lane & 15);
                af[t] = __builtin_bit_cast(bf16x8,
                    *(const uint4*)((const char*)Al + (((ar << 8) + kb) ^ ((ar & 7) << 4))));
                int br = wn + t * 16 + (lane & 15);
                bfr[t] = __builtin_bit_cast(bf16x8,
                    *(const uint4*)((const char*)Bl + (((br << 8) + kb) ^ ((br & 7) << 4))));
            }
#pragma unroll
            for (int i = 0; i < 4; ++i)
#pragma unroll
                for (int j = 0; j < 4; ++j)
                    acc[i][j] = __builtin_amdgcn_mfma_f32_16x16x32_bf16(af[i], bfr[j], acc[i][j], 0, 0, 0);
        }
    }

    const int cl = lane & 15, rg = lane >> 4;
#pragma unroll
    for (int j = 0; j < 4; ++j) {
        int gn = n0 + wn + j * 16 + cl;
        float bv = bias[gn];
        float sc = 0.f, sh = 0.f;
        if constexpr (EPI == 1) {
            sc = bng[gn] * rsqrtf(bnv[gn] + 1e-5f);
            sh = bnb[gn] - bnm[gn] * sc;
        }
#pragma unroll
        for (int i = 0; i < 4; ++i) {
#pragma unroll
            for (int r = 0; r < 4; ++r) {
                int gm = m0 + wm + i * 16 + rg * 4 + r;
                if (gm >= M) continue;
                float v = acc[i][j][r] + bv;
                if constexpr (EPI == 0) {
                    ((u16*)Cout)[(size_t)gm * 256 + gn] = f2bf(fmaxf(v, 0.f));
                } else if constexpr (EPI == 1) {
                    ((float*)Cout)[(size_t)gm * 256 + gn] = fmaxf(v * sc + sh, 0.f);
                } else {
                    addbuf[(size_t)gm * 256 + gn] += v;
                }
            }
        }
    }
}

// ---- mean pool per graph (sorted batch, contiguous segments) -> bf16 ----
__global__ __launch_bounds__(256) void k_pool(const float* __restrict__ h,
                                              const int* __restrict__ starts,
                                              u16* __restrict__ gbf)
{
    int g = blockIdx.x;
    int c = threadIdx.x;
    int s0 = starts[g], s1 = starts[g + 1];
    float sum = 0.f;
    for (int i = s0; i < s1; ++i) sum += h[(size_t)i * 256 + c];
    float cnt = (float)(s1 - s0);
    gbf[(size_t)g * 256 + c] = f2bf(sum / fmaxf(cnt, 1.0f));
}

// ---- head matvec: logits[m] = dot(Th[m,:], hW2) + hb2 ----
__global__ __launch_bounds__(256) void k_head(const u16* __restrict__ Th,
                                              const float* __restrict__ hW2,
                                              const float* __restrict__ hb2,
                                              float* __restrict__ out)
{
    int m = blockIdx.x * 4 + (threadIdx.x >> 6);
    int lane = threadIdx.x & 63;
    const ushort4 t = *(const ushort4*)&Th[(size_t)m * 256 + lane * 4];
    float s = bf2f(t.x) * hW2[lane * 4 + 0] + bf2f(t.y) * hW2[lane * 4 + 1] +
              bf2f(t.z) * hW2[lane * 4 + 2] + bf2f(t.w) * hW2[lane * 4 + 3];
#pragma unroll
    for (int o = 32; o > 0; o >>= 1) s += __shfl_down(s, o);
    if (lane == 0) out[m] = s + hb2[0];
}

extern "C" void kernel_launch(void* const* d_in, const int* in_sizes, int n_in,
                              void* d_out, int out_size, void* d_ws, size_t ws_size,
                              hipStream_t stream)
{
    const int*   x        = (const int*)d_in[0];
    const int*   ei       = (const int*)d_in[1];
    const int*   eattr    = (const int*)d_in[2];
    const int*   batch    = (const int*)d_in[3];
    const float* node_emb = (const float*)d_in[4];
    const float* edge_emb = (const float*)d_in[5];
    const float* vn_emb   = (const float*)d_in[6];
    const float* eps      = (const float*)d_in[7];
    const float* W1       = (const float*)d_in[8];
    const float* b1       = (const float*)d_in[9];
    const float* W2       = (const float*)d_in[10];
    const float* b2       = (const float*)d_in[11];
    const float* bng      = (const float*)d_in[12];
    const float* bnb      = (const float*)d_in[13];
    const float* bnm      = (const float*)d_in[14];
    const float* bnv      = (const float*)d_in[15];
    const float* vW1      = (const float*)d_in[16];
    const float* vb1      = (const float*)d_in[17];
    const float* vW2      = (const float*)d_in[18];
    const float* vb2      = (const float*)d_in[19];
    const float* hW1      = (const float*)d_in[20];
    const float* hb1      = (const float*)d_in[21];
    const float* hW2      = (const float*)d_in[22];
    const float* hb2      = (const float*)d_in[23];
    float* out = (float*)d_out;

    char* ws = (char*)d_ws;
    size_t off = 0;
    auto alloc = [&](size_t b) {
        char* p = ws + off;
        off = (off + b + 255) & ~(size_t)255;
        return p;
    };
    float* h    = (float*)alloc((size_t)NN * 256 * 4);
    u16*   Abf  = (u16*)alloc((size_t)NN * 256 * 2);
    u16*   T    = (u16*)alloc((size_t)NN * 256 * 2);
    float* vn   = (float*)alloc((size_t)NG * 256 * 4);
    u16*   gbf  = (u16*)alloc((size_t)NG * 256 * 2);
    u16*   Tg   = (u16*)alloc((size_t)NG * 256 * 2);
    u16*   Wt   = (u16*)alloc((size_t)21 * 65536 * 2);
    int*   starts = (int*)alloc((size_t)(NG + 1) * 4);
    float* comb = (float*)alloc((size_t)60 * 256 * 4);
    int*   deg  = (int*)alloc((size_t)NN * 4);
    u32*   slots = (u32*)alloc((size_t)NN * CAP * 4);

    const int* srcI = ei;
    const int* dstI = ei + NE;

    k_prep_weights<<<21 * 256, 256, 0, stream>>>(W1, W2, vW1, vW2, hW1, Wt);
    k_comb<<<60, 256, 0, stream>>>(edge_emb, comb);
    k_starts<<<(NG + 1 + 255) / 256, 256, 0, stream>>>(batch, starts);
    k_vn_init<<<NG, 256, 0, stream>>>(vn_emb, vn);
    k_embed<<<NN / 4, 256, 0, stream>>>(x, node_emb, h);
    hipMemsetAsync(deg, 0, (size_t)NN * 4, stream);
    k_bucket<<<(NE + 255) / 256, 256, 0, stream>>>(srcI, dstI, eattr, deg, slots);

    const int GBIG = ((NN + 127) / 128) * 2;  // 938 blocks
    const int GSMALL = (NG / 128) * 2;        // 32 blocks

    for (int l = 0; l < NL; ++l) {
        k_agg<<<NN / 4, 256, 0, stream>>>(h, vn, batch, slots, deg, comb, Abf, eps + l);
        k_gemm<0><<<GBIG, 256, 0, stream>>>(Abf, Wt + (size_t)(0 + l) * 65536, T,
                                            b1 + l * 256, nullptr, nullptr, nullptr, nullptr,
                                            nullptr, NN);
        k_gemm<1><<<GBIG, 256, 0, stream>>>(T, Wt + (size_t)(5 + l) * 65536, h,
                                            b2 + l * 256, bng + l * 256, bnb + l * 256,
                                            bnm + l * 256, bnv + l * 256, nullptr, NN);
        k_pool<<<NG, 256, 0, stream>>>(h, starts, gbf);
        k_gemm<0><<<GSMALL, 256, 0, stream>>>(gbf, Wt + (size_t)(10 + l) * 65536, Tg,
                                              vb1 + l * 256, nullptr, nullptr, nullptr, nullptr,
                                              nullptr, NG);
        k_gemm<2><<<GSMALL, 256, 0, stream>>>(Tg, Wt + (size_t)(15 + l) * 65536, nullptr,
                                              vb2 + l * 256, nullptr, nullptr, nullptr, nullptr,
                                              vn, NG);
    }
    k_pool<<<NG, 256, 0, stream>>>(h, starts, gbf);
    k_gemm<0><<<GSMALL, 256, 0, stream>>>(gbf, Wt + (size_t)20 * 65536, Tg,
                                          hb1, nullptr, nullptr, nullptr, nullptr,
                                          nullptr, NG);
    k_head<<<NG / 4, 256, 0, stream>>>(Tg, hW2, hb2, out);
}

// Round 3
// 789.309 us; speedup vs baseline: 4.9693x; 1.2616x over previous
//
#include <hip/hip_runtime.h>

#define NN 60000
#define NE 180000
#define NG 2048
#define HD 256
#define NL 5
#define CAP 32

typedef unsigned short u16;
typedef unsigned int u32;
typedef __bf16 bf16x8 __attribute__((ext_vector_type(8)));
typedef float f32x4 __attribute__((ext_vector_type(4)));

__device__ __forceinline__ u16 f2bf(float f) {
    u32 u = __builtin_bit_cast(u32, f);
    u += 0x7FFFu + ((u >> 16) & 1u);
    return (u16)(u >> 16);
}
__device__ __forceinline__ float bf2f(u16 s) {
    return __builtin_bit_cast(float, (u32)s << 16);
}
__device__ __forceinline__ void gload_lds16(const void* g, void* l) {
    __builtin_amdgcn_global_load_lds(
        (const __attribute__((address_space(1))) unsigned int*)g,
        (__attribute__((address_space(3))) unsigned int*)l, 16, 0, 0);
}

__constant__ int NODE_OFF[9]  = {0, 119, 124, 136, 148, 158, 164, 170, 172};
__constant__ int NODE_MAXC[9] = {118, 4, 11, 11, 9, 5, 5, 1, 1};

// ---- transpose + bf16-cast the 21 256x256 weight matrices ----
__global__ __launch_bounds__(256) void k_prep_weights(
    const float* __restrict__ W1, const float* __restrict__ W2,
    const float* __restrict__ vW1, const float* __restrict__ vW2,
    const float* __restrict__ hW1, u16* __restrict__ Wt)
{
    int mat = blockIdx.x >> 8;
    int n = blockIdx.x & 255;
    int k = threadIdx.x;
    const float* src;
    if (mat < 5)       src = W1 + (size_t)mat * 65536;
    else if (mat < 10) src = W2 + (size_t)(mat - 5) * 65536;
    else if (mat < 15) src = vW1 + (size_t)(mat - 10) * 65536;
    else if (mat < 20) src = vW2 + (size_t)(mat - 15) * 65536;
    else               src = hW1;
    Wt[(size_t)mat * 65536 + n * 256 + k] = f2bf(src[k * 256 + n]);
}

// ---- combined edge-attr embedding table (bf16): 60 rows (5*6*2) x 256 ----
__global__ __launch_bounds__(256) void k_comb(const float* __restrict__ eemb,
                                              u16* __restrict__ comb)
{
    int r = blockIdx.x;
    int c = threadIdx.x;
    int a0 = r / 12, a1 = (r % 12) / 2, a2 = r & 1;
    comb[r * 256 + c] = f2bf(eemb[(0 + a0) * 256 + c] + eemb[(5 + a1) * 256 + c] +
                             eemb[(11 + a2) * 256 + c]);
}

// ---- per-graph segment starts via binary search (batch is sorted) ----
__global__ __launch_bounds__(256) void k_starts(const int* __restrict__ batch,
                                                int* __restrict__ starts)
{
    int g = blockIdx.x * 256 + threadIdx.x;
    if (g > NG) return;
    int lo = 0, hi = NN;
    while (lo < hi) {
        int mid = (lo + hi) >> 1;
        if (batch[mid] < g) lo = mid + 1; else hi = mid;
    }
    starts[g] = lo;
}

__global__ __launch_bounds__(256) void k_vn_init(const float* __restrict__ vn_emb,
                                                 float* __restrict__ vn,
                                                 u16* __restrict__ vnbf)
{
    int i = blockIdx.x * 256 + threadIdx.x;
    float v = vn_emb[i & 255];
    vn[i] = v;
    vnbf[i] = f2bf(v);
}

// ---- node embedding: h = sum of 9 table rows -> bf16 ----
__global__ __launch_bounds__(256) void k_embed(const int* __restrict__ x,
                                               const float* __restrict__ node_emb,
                                               u16* __restrict__ hbf)
{
    int i = blockIdx.x * 4 + (threadIdx.x >> 6);
    if (i >= NN) return;
    int c = (threadIdx.x & 63) * 4;
    float4 s = make_float4(0.f, 0.f, 0.f, 0.f);
#pragma unroll
    for (int f = 0; f < 9; ++f) {
        int xv = x[i * 9 + f];
        xv = xv < 0 ? 0 : (xv > NODE_MAXC[f] ? NODE_MAXC[f] : xv);
        const float4 t = *(const float4*)&node_emb[(size_t)(NODE_OFF[f] + xv) * 256 + c];
        s.x += t.x; s.y += t.y; s.z += t.z; s.w += t.w;
    }
    ushort4 o;
    o.x = f2bf(s.x); o.y = f2bf(s.y); o.z = f2bf(s.z); o.w = f2bf(s.w);
    *(ushort4*)&hbf[(size_t)i * 256 + c] = o;
}

// ---- CSR-bucket build: slots[d*CAP+p] = src | code<<17 ----
__global__ __launch_bounds__(256) void k_bucket(
    const int* __restrict__ src, const int* __restrict__ dst,
    const int* __restrict__ eattr, int* __restrict__ deg, u32* __restrict__ slots)
{
    int e = blockIdx.x * 256 + threadIdx.x;
    if (e >= NE) return;
    int a0 = eattr[e * 3 + 0]; a0 = a0 < 0 ? 0 : (a0 > 4 ? 4 : a0);
    int a1 = eattr[e * 3 + 1]; a1 = a1 < 0 ? 0 : (a1 > 5 ? 5 : a1);
    int a2 = eattr[e * 3 + 2]; a2 = a2 < 0 ? 0 : (a2 > 1 ? 1 : a2);
    u32 code = (u32)(a0 * 12 + a1 * 2 + a2);
    int d = dst[e];
    int p = atomicAdd(&deg[d], 1);
    if (p < CAP) slots[(size_t)d * CAP + p] = (u32)src[e] | (code << 17);
}

// ---- fused aggregation + A-prep (all-bf16 reads):
//   acc = sum_e relu(h[src]+vn[batch[src]]+comb[code])
//   A[d] = bf16((1+eps)*(h[d]+vn[batch[d]]) + acc)
__global__ __launch_bounds__(256) void k_agg(
    const u16* __restrict__ hbf, const u16* __restrict__ vnbf,
    const int* __restrict__ batch, const u32* __restrict__ slots,
    const int* __restrict__ deg, const u16* __restrict__ comb,
    u16* __restrict__ Abf, const float* __restrict__ epsp)
{
    int d = blockIdx.x * 4 + (threadIdx.x >> 6);
    int lane = threadIdx.x & 63;
    int c = lane * 4;
    int nd = deg[d];
    nd = nd > CAP ? CAP : nd;

    const u32* sl = slots + (size_t)d * CAP;
    u32 sv_l = (lane < nd) ? sl[lane] : 0u;
    int b_l = (lane < nd) ? batch[sv_l & 0x1FFFFu] : 0;

    float4 acc = make_float4(0.f, 0.f, 0.f, 0.f);
    for (int p = 0; p < nd; ++p) {
        u32 sv = (u32)__shfl((int)sv_l, p);
        int b  = __shfl(b_l, p);
        int s  = (int)(sv & 0x1FFFFu);
        int code = (int)(sv >> 17);
        const ushort4 hv = *(const ushort4*)&hbf[(size_t)s * 256 + c];
        const ushort4 vv = *(const ushort4*)&vnbf[(size_t)b * 256 + c];
        const ushort4 tv = *(const ushort4*)&comb[(size_t)code * 256 + c];
        acc.x += fmaxf(bf2f(hv.x) + bf2f(vv.x) + bf2f(tv.x), 0.f);
        acc.y += fmaxf(bf2f(hv.y) + bf2f(vv.y) + bf2f(tv.y), 0.f);
        acc.z += fmaxf(bf2f(hv.z) + bf2f(vv.z) + bf2f(tv.z), 0.f);
        acc.w += fmaxf(bf2f(hv.w) + bf2f(vv.w) + bf2f(tv.w), 0.f);
    }

    int bd = batch[d];
    float ep = 1.0f + *epsp;
    const ushort4 hd = *(const ushort4*)&hbf[(size_t)d * 256 + c];
    const ushort4 vd = *(const ushort4*)&vnbf[(size_t)bd * 256 + c];
    ushort4 o;
    o.x = f2bf((bf2f(hd.x) + bf2f(vd.x)) * ep + acc.x);
    o.y = f2bf((bf2f(hd.y) + bf2f(vd.y)) * ep + acc.y);
    o.z = f2bf((bf2f(hd.z) + bf2f(vd.z)) * ep + acc.z);
    o.w = f2bf((bf2f(hd.w) + bf2f(vd.w)) * ep + acc.w);
    *(ushort4*)&Abf[(size_t)d * 256 + c] = o;
}

// ---- big GEMM: C[M,256] = A[M,256] @ B, BM=128, BN=256, BK=64, 8 waves.
// A bf16 row-major, Bt pre-transposed bf16 [n][k].
// global_load_lds staging: linear LDS dest, inverse-swizzled global source,
// XOR-swizzle on ds_read (chunk ^= row&7; 2-way bank alias = free).
// EPI 0: out = bf16(relu(acc+bias))   EPI 1: out = bf16(relu(BN(acc+bias)))
template <int EPI>
__global__ __launch_bounds__(512) void k_gemmL(
    const u16* __restrict__ A, const u16* __restrict__ Bt,
    u16* __restrict__ Cout, const float* __restrict__ bias,
    const float* __restrict__ bng, const float* __restrict__ bnb,
    const float* __restrict__ bnm, const float* __restrict__ bnv, int M)
{
    __shared__ __align__(16) u16 Al[128 * 64];  // 16 KB
    __shared__ __align__(16) u16 Bl[256 * 64];  // 32 KB
    const int m0 = blockIdx.x * 128;
    const int tid = threadIdx.x, lane = tid & 63, wid = tid >> 6;
    const int wm = (wid >> 2) * 64, wn = (wid & 3) * 64;
    f32x4 acc[4][4] = {};

    for (int k0 = 0; k0 < 256; k0 += 64) {
        __syncthreads();  // prior reads of LDS done
        // stage A: 1024 16B-slots, 512 threads -> 2 rounds
#pragma unroll
        for (int i = 0; i < 2; ++i) {
            int slot = i * 512 + tid;
            int row = slot >> 3, cch = slot & 7;
            int g = cch ^ (row & 7);  // inverse-swizzled source chunk
            gload_lds16((const char*)A + (size_t)(m0 + row) * 512 + (size_t)k0 * 2 + (g << 4),
                        (char*)Al + ((i * 512 + wid * 64) << 4));
        }
        // stage B: 2048 slots -> 4 rounds
#pragma unroll
        for (int i = 0; i < 4; ++i) {
            int slot = i * 512 + tid;
            int row = slot >> 3, cch = slot & 7;
            int g = cch ^ (row & 7);
            gload_lds16((const char*)Bt + (size_t)row * 512 + (size_t)k0 * 2 + (g << 4),
                        (char*)Bl + ((i * 512 + wid * 64) << 4));
        }
        __syncthreads();  // drains vmcnt (compiler inserts waitcnt before barrier)

#pragma unroll
        for (int kw = 0; kw < 2; ++kw) {
            int q = kw * 4 + (lane >> 4);
            bf16x8 af[4], bfr[4];
#pragma unroll
            for (int t = 0; t < 4; ++t) {
                int ar = wm + t * 16 + (lane & 15);
                af[t] = __builtin_bit_cast(bf16x8,
                    *(const uint4*)((const char*)Al + (ar << 7) + ((q ^ (ar & 7)) << 4)));
                int br = wn + t * 16 + (lane & 15);
                bfr[t] = __builtin_bit_cast(bf16x8,
                    *(const uint4*)((const char*)Bl + (br << 7) + ((q ^ (br & 7)) << 4)));
            }
#pragma unroll
            for (int i = 0; i < 4; ++i)
#pragma unroll
                for (int j = 0; j < 4; ++j)
                    acc[i][j] = __builtin_amdgcn_mfma_f32_16x16x32_bf16(af[i], bfr[j], acc[i][j], 0, 0, 0);
        }
    }

    const int cl = lane & 15, rg = lane >> 4;
#pragma unroll
    for (int j = 0; j < 4; ++j) {
        int gn = wn + j * 16 + cl;
        float bv = bias[gn];
        float sc = 0.f, sh = 0.f;
        if constexpr (EPI == 1) {
            sc = bng[gn] * rsqrtf(bnv[gn] + 1e-5f);
            sh = bnb[gn] - bnm[gn] * sc;
        }
#pragma unroll
        for (int i = 0; i < 4; ++i) {
#pragma unroll
            for (int r = 0; r < 4; ++r) {
                int gm = m0 + wm + i * 16 + rg * 4 + r;
                if (gm >= M) continue;
                float v = acc[i][j][r] + bv;
                if constexpr (EPI == 0) {
                    Cout[(size_t)gm * 256 + gn] = f2bf(fmaxf(v, 0.f));
                } else {
                    Cout[(size_t)gm * 256 + gn] = f2bf(fmaxf(v * sc + sh, 0.f));
                }
            }
        }
    }
}

// ---- small GEMM (M=2048): 128x128 tile, manual staging (kept from r1)
// EPI 0: out = bf16(relu(acc+bias))   EPI 2: vn += acc+bias; vnbf = bf16(vn)
template <int EPI>
__global__ __launch_bounds__(256) void k_gemm_sm(
    const u16* __restrict__ A, const u16* __restrict__ Bt,
    u16* __restrict__ Cout, const float* __restrict__ bias,
    float* __restrict__ addbuf, u16* __restrict__ addbf, int M)
{
    __shared__ __align__(16) u16 Asl[128 * 128];
    __shared__ __align__(16) u16 Bsl[128 * 128];
    const int bm = blockIdx.x >> 1, bn = blockIdx.x & 1;
    const int m0 = bm * 128, n0 = bn * 128;
    const int tid = threadIdx.x, lane = tid & 63, wid = tid >> 6;
    const int wm = (wid >> 1) * 64, wn = (wid & 1) * 64;
    f32x4 acc[4][4] = {};

    for (int k0 = 0; k0 < 256; k0 += 128) {
        __syncthreads();
#pragma unroll
        for (int it = 0; it < 8; ++it) {
            int cch = it * 256 + tid;
            int row = cch >> 4, col = cch & 15;
            int lofs = ((row << 8) + (col << 4)) ^ ((row & 7) << 4);
            uint4 va = *(const uint4*)((const char*)A + ((size_t)(m0 + row) * 512 + (size_t)k0 * 2 + (col << 4)));
            *(uint4*)((char*)Asl + lofs) = va;
            uint4 vb = *(const uint4*)((const char*)Bt + ((size_t)(n0 + row) * 512 + (size_t)k0 * 2 + (col << 4)));
            *(uint4*)((char*)Bsl + lofs) = vb;
        }
        __syncthreads();
#pragma unroll
        for (int kt = 0; kt < 4; ++kt) {
            bf16x8 af[4], bfr[4];
            int kb = kt * 64 + ((lane >> 4) << 4);
#pragma unroll
            for (int t = 0; t < 4; ++t) {
                int ar = wm + t * 16 + (lane & 15);
                af[t] = __builtin_bit_cast(bf16x8,
                    *(const uint4*)((const char*)Asl + (((ar << 8) + kb) ^ ((ar & 7) << 4))));
                int br = wn + t * 16 + (lane & 15);
                bfr[t] = __builtin_bit_cast(bf16x8,
                    *(const uint4*)((const char*)Bsl + (((br << 8) + kb) ^ ((br & 7) << 4))));
            }
#pragma unroll
            for (int i = 0; i < 4; ++i)
#pragma unroll
                for (int j = 0; j < 4; ++j)
                    acc[i][j] = __builtin_amdgcn_mfma_f32_16x16x32_bf16(af[i], bfr[j], acc[i][j], 0, 0, 0);
        }
    }

    const int cl = lane & 15, rg = lane >> 4;
#pragma unroll
    for (int j = 0; j < 4; ++j) {
        int gn = n0 + wn + j * 16 + cl;
        float bv = bias[gn];
#pragma unroll
        for (int i = 0; i < 4; ++i) {
#pragma unroll
            for (int r = 0; r < 4; ++r) {
                int gm = m0 + wm + i * 16 + rg * 4 + r;
                if (gm >= M) continue;
                float v = acc[i][j][r] + bv;
                if constexpr (EPI == 0) {
                    Cout[(size_t)gm * 256 + gn] = f2bf(fmaxf(v, 0.f));
                } else {
                    size_t idx = (size_t)gm * 256 + gn;
                    float nv = addbuf[idx] + v;
                    addbuf[idx] = nv;
                    addbf[idx] = f2bf(nv);
                }
            }
        }
    }
}

// ---- mean pool per graph (sorted batch, contiguous segments) -> bf16 ----
__global__ __launch_bounds__(256) void k_pool(const u16* __restrict__ hbf,
                                              const int* __restrict__ starts,
                                              u16* __restrict__ gbf)
{
    int g = blockIdx.x;
    int c = threadIdx.x;
    int s0 = starts[g], s1 = starts[g + 1];
    float sum = 0.f;
    for (int i = s0; i < s1; ++i) sum += bf2f(hbf[(size_t)i * 256 + c]);
    float cnt = (float)(s1 - s0);
    gbf[(size_t)g * 256 + c] = f2bf(sum / fmaxf(cnt, 1.0f));
}

// ---- head matvec: logits[m] = dot(Th[m,:], hW2) + hb2 ----
__global__ __launch_bounds__(256) void k_head(const u16* __restrict__ Th,
                                              const float* __restrict__ hW2,
                                              const float* __restrict__ hb2,
                                              float* __restrict__ out)
{
    int m = blockIdx.x * 4 + (threadIdx.x >> 6);
    int lane = threadIdx.x & 63;
    const ushort4 t = *(const ushort4*)&Th[(size_t)m * 256 + lane * 4];
    float s = bf2f(t.x) * hW2[lane * 4 + 0] + bf2f(t.y) * hW2[lane * 4 + 1] +
              bf2f(t.z) * hW2[lane * 4 + 2] + bf2f(t.w) * hW2[lane * 4 + 3];
#pragma unroll
    for (int o = 32; o > 0; o >>= 1) s += __shfl_down(s, o);
    if (lane == 0) out[m] = s + hb2[0];
}

extern "C" void kernel_launch(void* const* d_in, const int* in_sizes, int n_in,
                              void* d_out, int out_size, void* d_ws, size_t ws_size,
                              hipStream_t stream)
{
    const int*   x        = (const int*)d_in[0];
    const int*   ei       = (const int*)d_in[1];
    const int*   eattr    = (const int*)d_in[2];
    const int*   batch    = (const int*)d_in[3];
    const float* node_emb = (const float*)d_in[4];
    const float* edge_emb = (const float*)d_in[5];
    const float* vn_emb   = (const float*)d_in[6];
    const float* eps      = (const float*)d_in[7];
    const float* W1       = (const float*)d_in[8];
    const float* b1       = (const float*)d_in[9];
    const float* W2       = (const float*)d_in[10];
    const float* b2       = (const float*)d_in[11];
    const float* bng      = (const float*)d_in[12];
    const float* bnb      = (const float*)d_in[13];
    const float* bnm      = (const float*)d_in[14];
    const float* bnv      = (const float*)d_in[15];
    const float* vW1      = (const float*)d_in[16];
    const float* vb1      = (const float*)d_in[17];
    const float* vW2      = (const float*)d_in[18];
    const float* vb2      = (const float*)d_in[19];
    const float* hW1      = (const float*)d_in[20];
    const float* hb1      = (const float*)d_in[21];
    const float* hW2      = (const float*)d_in[22];
    const float* hb2      = (const float*)d_in[23];
    float* out = (float*)d_out;

    char* ws = (char*)d_ws;
    size_t off = 0;
    auto alloc = [&](size_t b) {
        char* p = ws + off;
        off = (off + b + 255) & ~(size_t)255;
        return p;
    };
    u16*   hbf  = (u16*)alloc((size_t)NN * 256 * 2);
    u16*   Abf  = (u16*)alloc((size_t)NN * 256 * 2);
    u16*   T    = (u16*)alloc((size_t)NN * 256 * 2);
    float* vn   = (float*)alloc((size_t)NG * 256 * 4);
    u16*   vnbf = (u16*)alloc((size_t)NG * 256 * 2);
    u16*   gbf  = (u16*)alloc((size_t)NG * 256 * 2);
    u16*   Tg   = (u16*)alloc((size_t)NG * 256 * 2);
    u16*   Wt   = (u16*)alloc((size_t)21 * 65536 * 2);
    int*   starts = (int*)alloc((size_t)(NG + 1) * 4);
    u16*   comb = (u16*)alloc((size_t)60 * 256 * 2);
    int*   deg  = (int*)alloc((size_t)NN * 4);
    u32*   slots = (u32*)alloc((size_t)NN * CAP * 4);

    const int* srcI = ei;
    const int* dstI = ei + NE;

    k_prep_weights<<<21 * 256, 256, 0, stream>>>(W1, W2, vW1, vW2, hW1, Wt);
    k_comb<<<60, 256, 0, stream>>>(edge_emb, comb);
    k_starts<<<(NG + 1 + 255) / 256, 256, 0, stream>>>(batch, starts);
    k_vn_init<<<NG, 256, 0, stream>>>(vn_emb, vn, vnbf);
    k_embed<<<NN / 4, 256, 0, stream>>>(x, node_emb, hbf);
    hipMemsetAsync(deg, 0, (size_t)NN * 4, stream);
    k_bucket<<<(NE + 255) / 256, 256, 0, stream>>>(srcI, dstI, eattr, deg, slots);

    const int GBIG = (NN + 127) / 128;    // 469 blocks
    const int GSMALL = (NG / 128) * 2;    // 32 blocks

    for (int l = 0; l < NL; ++l) {
        k_agg<<<NN / 4, 256, 0, stream>>>(hbf, vnbf, batch, slots, deg, comb, Abf, eps + l);
        k_gemmL<0><<<GBIG, 512, 0, stream>>>(Abf, Wt + (size_t)(0 + l) * 65536, T,
                                             b1 + l * 256, nullptr, nullptr, nullptr, nullptr, NN);
        k_gemmL<1><<<GBIG, 512, 0, stream>>>(T, Wt + (size_t)(5 + l) * 65536, hbf,
                                             b2 + l * 256, bng + l * 256, bnb + l * 256,
                                             bnm + l * 256, bnv + l * 256, NN);
        k_pool<<<NG, 256, 0, stream>>>(hbf, starts, gbf);
        k_gemm_sm<0><<<GSMALL, 256, 0, stream>>>(gbf, Wt + (size_t)(10 + l) * 65536, Tg,
                                                 vb1 + l * 256, nullptr, nullptr, NG);
        k_gemm_sm<2><<<GSMALL, 256, 0, stream>>>(Tg, Wt + (size_t)(15 + l) * 65536, nullptr,
                                                 vb2 + l * 256, vn, vnbf, NG);
    }
    k_pool<<<NG, 256, 0, stream>>>(hbf, starts, gbf);
    k_gemm_sm<0><<<GSMALL, 256, 0, stream>>>(gbf, Wt + (size_t)20 * 65536, Tg,
                                             hb1, nullptr, nullptr, NG);
    k_head<<<NG / 4, 256, 0, stream>>>(Tg, hW2, hb2, out);
}

// Round 4
// 620.231 us; speedup vs baseline: 6.3239x; 1.2726x over previous
//
#include <hip/hip_runtime.h>

#define NN 60000
#define NE 180000
#define NG 2048
#define HD 256
#define NL 5
#define CAP 32

typedef unsigned short u16;
typedef unsigned int u32;
typedef __bf16 bf16x8 __attribute__((ext_vector_type(8)));
typedef float f32x4 __attribute__((ext_vector_type(4)));

__device__ __forceinline__ u16 f2bf(float f) {
    u32 u = __builtin_bit_cast(u32, f);
    u += 0x7FFFu + ((u >> 16) & 1u);
    return (u16)(u >> 16);
}
__device__ __forceinline__ float bf2f(u16 s) {
    return __builtin_bit_cast(float, (u32)s << 16);
}
__device__ __forceinline__ void gload_lds16(const void* g, void* l) {
    __builtin_amdgcn_global_load_lds(
        (const __attribute__((address_space(1))) unsigned int*)g,
        (__attribute__((address_space(3))) unsigned int*)l, 16, 0, 0);
}

__constant__ int NODE_OFF[9]  = {0, 119, 124, 136, 148, 158, 164, 170, 172};
__constant__ int NODE_MAXC[9] = {118, 4, 11, 11, 9, 5, 5, 1, 1};

// ---- transpose + bf16-cast the 21 256x256 weight matrices ----
__global__ __launch_bounds__(256) void k_prep_weights(
    const float* __restrict__ W1, const float* __restrict__ W2,
    const float* __restrict__ vW1, const float* __restrict__ vW2,
    const float* __restrict__ hW1, u16* __restrict__ Wt)
{
    int mat = blockIdx.x >> 8;
    int n = blockIdx.x & 255;
    int k = threadIdx.x;
    const float* src;
    if (mat < 5)       src = W1 + (size_t)mat * 65536;
    else if (mat < 10) src = W2 + (size_t)(mat - 5) * 65536;
    else if (mat < 15) src = vW1 + (size_t)(mat - 10) * 65536;
    else if (mat < 20) src = vW2 + (size_t)(mat - 15) * 65536;
    else               src = hW1;
    Wt[(size_t)mat * 65536 + n * 256 + k] = f2bf(src[k * 256 + n]);
}

// ---- combined edge-attr embedding table (bf16): 60 rows (5*6*2) x 256 ----
__global__ __launch_bounds__(256) void k_comb(const float* __restrict__ eemb,
                                              u16* __restrict__ comb)
{
    int r = blockIdx.x;
    int c = threadIdx.x;
    int a0 = r / 12, a1 = (r % 12) / 2, a2 = r & 1;
    comb[r * 256 + c] = f2bf(eemb[(0 + a0) * 256 + c] + eemb[(5 + a1) * 256 + c] +
                             eemb[(11 + a2) * 256 + c]);
}

// ---- per-graph segment starts via binary search (batch is sorted) ----
__global__ __launch_bounds__(256) void k_starts(const int* __restrict__ batch,
                                                int* __restrict__ starts)
{
    int g = blockIdx.x * 256 + threadIdx.x;
    if (g > NG) return;
    int lo = 0, hi = NN;
    while (lo < hi) {
        int mid = (lo + hi) >> 1;
        if (batch[mid] < g) lo = mid + 1; else hi = mid;
    }
    starts[g] = lo;
}

__global__ __launch_bounds__(256) void k_vn_init(const float* __restrict__ vn_emb,
                                                 float* __restrict__ vn,
                                                 u16* __restrict__ vnbf)
{
    int i = blockIdx.x * 256 + threadIdx.x;
    float v = vn_emb[i & 255];
    vn[i] = v;
    vnbf[i] = f2bf(v);
}

// ---- node embedding: h = sum of 9 table rows -> bf16 ----
__global__ __launch_bounds__(256) void k_embed(const int* __restrict__ x,
                                               const float* __restrict__ node_emb,
                                               u16* __restrict__ hbf)
{
    int i = blockIdx.x * 4 + (threadIdx.x >> 6);
    if (i >= NN) return;
    int c = (threadIdx.x & 63) * 4;
    float4 s = make_float4(0.f, 0.f, 0.f, 0.f);
#pragma unroll
    for (int f = 0; f < 9; ++f) {
        int xv = x[i * 9 + f];
        xv = xv < 0 ? 0 : (xv > NODE_MAXC[f] ? NODE_MAXC[f] : xv);
        const float4 t = *(const float4*)&node_emb[(size_t)(NODE_OFF[f] + xv) * 256 + c];
        s.x += t.x; s.y += t.y; s.z += t.z; s.w += t.w;
    }
    ushort4 o;
    o.x = f2bf(s.x); o.y = f2bf(s.y); o.z = f2bf(s.z); o.w = f2bf(s.w);
    *(ushort4*)&hbf[(size_t)i * 256 + c] = o;
}

// ---- CSR-bucket build: slots[d*CAP+p] = src | code<<17 ----
__global__ __launch_bounds__(256) void k_bucket(
    const int* __restrict__ src, const int* __restrict__ dst,
    const int* __restrict__ eattr, int* __restrict__ deg, u32* __restrict__ slots)
{
    int e = blockIdx.x * 256 + threadIdx.x;
    if (e >= NE) return;
    int a0 = eattr[e * 3 + 0]; a0 = a0 < 0 ? 0 : (a0 > 4 ? 4 : a0);
    int a1 = eattr[e * 3 + 1]; a1 = a1 < 0 ? 0 : (a1 > 5 ? 5 : a1);
    int a2 = eattr[e * 3 + 2]; a2 = a2 < 0 ? 0 : (a2 > 1 ? 1 : a2);
    u32 code = (u32)(a0 * 12 + a1 * 2 + a2);
    int d = dst[e];
    int p = atomicAdd(&deg[d], 1);
    if (p < CAP) slots[(size_t)d * CAP + p] = (u32)src[e] | (code << 17);
}

// ---- fused aggregation + A-prep (all-bf16 reads) ----
__global__ __launch_bounds__(256) void k_agg(
    const u16* __restrict__ hbf, const u16* __restrict__ vnbf,
    const int* __restrict__ batch, const u32* __restrict__ slots,
    const int* __restrict__ deg, const u16* __restrict__ comb,
    u16* __restrict__ Abf, const float* __restrict__ epsp)
{
    int d = blockIdx.x * 4 + (threadIdx.x >> 6);
    int lane = threadIdx.x & 63;
    int c = lane * 4;
    int nd = deg[d];
    nd = nd > CAP ? CAP : nd;

    const u32* sl = slots + (size_t)d * CAP;
    u32 sv_l = (lane < nd) ? sl[lane] : 0u;
    int b_l = (lane < nd) ? batch[sv_l & 0x1FFFFu] : 0;

    float4 acc = make_float4(0.f, 0.f, 0.f, 0.f);
    for (int p = 0; p < nd; ++p) {
        u32 sv = (u32)__shfl((int)sv_l, p);
        int b  = __shfl(b_l, p);
        int s  = (int)(sv & 0x1FFFFu);
        int code = (int)(sv >> 17);
        const ushort4 hv = *(const ushort4*)&hbf[(size_t)s * 256 + c];
        const ushort4 vv = *(const ushort4*)&vnbf[(size_t)b * 256 + c];
        const ushort4 tv = *(const ushort4*)&comb[(size_t)code * 256 + c];
        acc.x += fmaxf(bf2f(hv.x) + bf2f(vv.x) + bf2f(tv.x), 0.f);
        acc.y += fmaxf(bf2f(hv.y) + bf2f(vv.y) + bf2f(tv.y), 0.f);
        acc.z += fmaxf(bf2f(hv.z) + bf2f(vv.z) + bf2f(tv.z), 0.f);
        acc.w += fmaxf(bf2f(hv.w) + bf2f(vv.w) + bf2f(tv.w), 0.f);
    }

    int bd = batch[d];
    float ep = 1.0f + *epsp;
    const ushort4 hd = *(const ushort4*)&hbf[(size_t)d * 256 + c];
    const ushort4 vd = *(const ushort4*)&vnbf[(size_t)bd * 256 + c];
    ushort4 o;
    o.x = f2bf((bf2f(hd.x) + bf2f(vd.x)) * ep + acc.x);
    o.y = f2bf((bf2f(hd.y) + bf2f(vd.y)) * ep + acc.y);
    o.z = f2bf((bf2f(hd.z) + bf2f(vd.z)) * ep + acc.z);
    o.w = f2bf((bf2f(hd.w) + bf2f(vd.w)) * ep + acc.w);
    *(ushort4*)&Abf[(size_t)d * 256 + c] = o;
}

// ================= fused 2-layer MLP =================
// C = epi( relu(A@W1 + b1) @ W2 + b2 ), A bf16 [M,256], W1t/W2t pre-transposed [n][k].
// BM=64, BN=256, BK=64; 512 threads = 8 waves of 32x64 tiles.
// T parked in LDS (64x256 bf16, chunk-XOR swizzle) — no global round-trip.
// EPI 0: hbf = bf16(relu(BN(.)))   EPI 1: vn += .; vnbf = bf16(vn)
template <int EPI>
__global__ __launch_bounds__(512) void k_mlp(
    const u16* __restrict__ A, const u16* __restrict__ W1t, const u16* __restrict__ W2t,
    const float* __restrict__ b1, const float* __restrict__ b2,
    u16* __restrict__ hbf,
    const float* __restrict__ bng, const float* __restrict__ bnb,
    const float* __restrict__ bnm, const float* __restrict__ bnv,
    float* __restrict__ vn, u16* __restrict__ vnbf, int M)
{
    __shared__ __align__(16) u16 Al[64 * 64];    // 8 KB
    __shared__ __align__(16) u16 Bl[256 * 64];   // 32 KB
    __shared__ __align__(16) u16 Tl[64 * 256];   // 32 KB
    const int m0 = blockIdx.x * 64;
    const int tid = threadIdx.x, lane = tid & 63, wid = tid >> 6;
    const int wm = (wid >> 2) * 32, wn = (wid & 3) * 64;
    const int cl = lane & 15, rg = lane >> 4;
    f32x4 acc[2][4] = {};

    // ---- phase 1: T = relu(A @ W1 + b1) ----
    for (int k0 = 0; k0 < 256; k0 += 64) {
        __syncthreads();
        {   // stage A: 512 slots, 1 round
            int row = tid >> 3, cch = tid & 7;
            int g = cch ^ (row & 7);
            gload_lds16((const char*)A + (size_t)(m0 + row) * 512 + (size_t)k0 * 2 + (g << 4),
                        (char*)Al + ((wid * 64) << 4));
        }
#pragma unroll
        for (int i = 0; i < 4; ++i) {  // stage W1t: 2048 slots, 4 rounds
            int slot = i * 512 + tid;
            int row = slot >> 3, cch = slot & 7;
            int g = cch ^ (row & 7);
            gload_lds16((const char*)W1t + (size_t)row * 512 + (size_t)k0 * 2 + (g << 4),
                        (char*)Bl + ((i * 512 + wid * 64) << 4));
        }
        __syncthreads();
#pragma unroll
        for (int kw = 0; kw < 2; ++kw) {
            int q = kw * 4 + (lane >> 4);
            bf16x8 af[2], bfr[4];
#pragma unroll
            for (int t = 0; t < 2; ++t) {
                int ar = wm + t * 16 + cl;
                af[t] = __builtin_bit_cast(bf16x8,
                    *(const uint4*)((const char*)Al + (ar << 7) + ((q ^ (ar & 7)) << 4)));
            }
#pragma unroll
            for (int t = 0; t < 4; ++t) {
                int br = wn + t * 16 + cl;
                bfr[t] = __builtin_bit_cast(bf16x8,
                    *(const uint4*)((const char*)Bl + (br << 7) + ((q ^ (br & 7)) << 4)));
            }
#pragma unroll
            for (int i = 0; i < 2; ++i)
#pragma unroll
                for (int j = 0; j < 4; ++j)
                    acc[i][j] = __builtin_amdgcn_mfma_f32_16x16x32_bf16(af[i], bfr[j], acc[i][j], 0, 0, 0);
        }
    }

    // ---- T-write to LDS (bf16, chunk-XOR swizzle; 2/4-way bank alias tolerable) ----
#pragma unroll
    for (int j = 0; j < 4; ++j) {
        int col = wn + j * 16 + cl;
        float bv = b1[col];
#pragma unroll
        for (int i = 0; i < 2; ++i) {
#pragma unroll
            for (int r = 0; r < 4; ++r) {
                int row = wm + i * 16 + rg * 4 + r;
                float v = fmaxf(acc[i][j][r] + bv, 0.f);
                int byte = (row << 9) + ((((col >> 3) ^ (row & 7))) << 4) + ((col & 7) << 1);
                *(u16*)((char*)Tl + byte) = f2bf(v);
            }
        }
    }
    __syncthreads();

    // ---- phase 2: C = T @ W2 + b2 ----
    f32x4 acc2[2][4] = {};
    for (int k0 = 0; k0 < 256; k0 += 64) {
        if (k0) __syncthreads();
#pragma unroll
        for (int i = 0; i < 4; ++i) {  // stage W2t into Bl
            int slot = i * 512 + tid;
            int row = slot >> 3, cch = slot & 7;
            int g = cch ^ (row & 7);
            gload_lds16((const char*)W2t + (size_t)row * 512 + (size_t)k0 * 2 + (g << 4),
                        (char*)Bl + ((i * 512 + wid * 64) << 4));
        }
        __syncthreads();
#pragma unroll
        for (int kw = 0; kw < 2; ++kw) {
            int q = kw * 4 + (lane >> 4);
            int qt = (k0 >> 3) + q;      // global chunk in Tl row
            bf16x8 af[2], bfr[4];
#pragma unroll
            for (int t = 0; t < 2; ++t) {
                int ar = wm + t * 16 + cl;
                af[t] = __builtin_bit_cast(bf16x8,
                    *(const uint4*)((const char*)Tl + (ar << 9) + ((qt ^ (ar & 7)) << 4)));
            }
#pragma unroll
            for (int t = 0; t < 4; ++t) {
                int br = wn + t * 16 + cl;
                bfr[t] = __builtin_bit_cast(bf16x8,
                    *(const uint4*)((const char*)Bl + (br << 7) + ((q ^ (br & 7)) << 4)));
            }
#pragma unroll
            for (int i = 0; i < 2; ++i)
#pragma unroll
                for (int j = 0; j < 4; ++j)
                    acc2[i][j] = __builtin_amdgcn_mfma_f32_16x16x32_bf16(af[i], bfr[j], acc2[i][j], 0, 0, 0);
        }
    }

    // ---- epilogue ----
#pragma unroll
    for (int j = 0; j < 4; ++j) {
        int gn = wn + j * 16 + cl;
        float bv = b2[gn];
        float sc = 0.f, sh = 0.f;
        if constexpr (EPI == 0) {
            sc = bng[gn] * rsqrtf(bnv[gn] + 1e-5f);
            sh = bnb[gn] - bnm[gn] * sc;
        }
#pragma unroll
        for (int i = 0; i < 2; ++i) {
#pragma unroll
            for (int r = 0; r < 4; ++r) {
                int gm = m0 + wm + i * 16 + rg * 4 + r;
                if (gm >= M) continue;
                float v = acc2[i][j][r] + bv;
                if constexpr (EPI == 0) {
                    hbf[(size_t)gm * 256 + gn] = f2bf(fmaxf(v * sc + sh, 0.f));
                } else {
                    size_t idx = (size_t)gm * 256 + gn;
                    float nv = vn[idx] + v;
                    vn[idx] = nv;
                    vnbf[idx] = f2bf(nv);
                }
            }
        }
    }
}

// ---- fused head: T = relu(gbf@hW1+hb1) in LDS, then logits = T@hW2 + hb2 ----
__global__ __launch_bounds__(512) void k_headf(
    const u16* __restrict__ A, const u16* __restrict__ W1t,
    const float* __restrict__ b1, const float* __restrict__ hW2,
    const float* __restrict__ hb2, float* __restrict__ out)
{
    __shared__ __align__(16) u16 Al[64 * 64];
    __shared__ __align__(16) u16 Bl[256 * 64];
    __shared__ __align__(16) u16 Tl[64 * 256];
    const int m0 = blockIdx.x * 64;
    const int tid = threadIdx.x, lane = tid & 63, wid = tid >> 6;
    const int wm = (wid >> 2) * 32, wn = (wid & 3) * 64;
    const int cl = lane & 15, rg = lane >> 4;
    f32x4 acc[2][4] = {};

    for (int k0 = 0; k0 < 256; k0 += 64) {
        __syncthreads();
        {
            int row = tid >> 3, cch = tid & 7;
            int g = cch ^ (row & 7);
            gload_lds16((const char*)A + (size_t)(m0 + row) * 512 + (size_t)k0 * 2 + (g << 4),
                        (char*)Al + ((wid * 64) << 4));
        }
#pragma unroll
        for (int i = 0; i < 4; ++i) {
            int slot = i * 512 + tid;
            int row = slot >> 3, cch = slot & 7;
            int g = cch ^ (row & 7);
            gload_lds16((const char*)W1t + (size_t)row * 512 + (size_t)k0 * 2 + (g << 4),
                        (char*)Bl + ((i * 512 + wid * 64) << 4));
        }
        __syncthreads();
#pragma unroll
        for (int kw = 0; kw < 2; ++kw) {
            int q = kw * 4 + (lane >> 4);
            bf16x8 af[2], bfr[4];
#pragma unroll
            for (int t = 0; t < 2; ++t) {
                int ar = wm + t * 16 + cl;
                af[t] = __builtin_bit_cast(bf16x8,
                    *(const uint4*)((const char*)Al + (ar << 7) + ((q ^ (ar & 7)) << 4)));
            }
#pragma unroll
            for (int t = 0; t < 4; ++t) {
                int br = wn + t * 16 + cl;
                bfr[t] = __builtin_bit_cast(bf16x8,
                    *(const uint4*)((const char*)Bl + (br << 7) + ((q ^ (br & 7)) << 4)));
            }
#pragma unroll
            for (int i = 0; i < 2; ++i)
#pragma unroll
                for (int j = 0; j < 4; ++j)
                    acc[i][j] = __builtin_amdgcn_mfma_f32_16x16x32_bf16(af[i], bfr[j], acc[i][j], 0, 0, 0);
        }
    }
#pragma unroll
    for (int j = 0; j < 4; ++j) {
        int col = wn + j * 16 + cl;
        float bv = b1[col];
#pragma unroll
        for (int i = 0; i < 2; ++i) {
#pragma unroll
            for (int r = 0; r < 4; ++r) {
                int row = wm + i * 16 + rg * 4 + r;
                float v = fmaxf(acc[i][j][r] + bv, 0.f);
                int byte = (row << 9) + ((((col >> 3) ^ (row & 7))) << 4) + ((col & 7) << 1);
                *(u16*)((char*)Tl + byte) = f2bf(v);
            }
        }
    }
    __syncthreads();

    // matvec: 8 threads per row
    int row = tid >> 3, oct = tid & 7;
    float s = 0.f;
#pragma unroll
    for (int c = 0; c < 32; ++c) {
        int col = oct * 32 + c;
        int byte = (row << 9) + ((((col >> 3) ^ (row & 7))) << 4) + ((col & 7) << 1);
        s += bf2f(*(const u16*)((const char*)Tl + byte)) * hW2[col];
    }
    s += __shfl_down(s, 4);
    s += __shfl_down(s, 2);
    s += __shfl_down(s, 1);
    if (oct == 0) out[m0 + row] = s + hb2[0];
}

// ---- mean pool per graph (sorted batch, contiguous segments) -> bf16 ----
__global__ __launch_bounds__(256) void k_pool(const u16* __restrict__ hbf,
                                              const int* __restrict__ starts,
                                              u16* __restrict__ gbf)
{
    int g = blockIdx.x;
    int c = threadIdx.x;
    int s0 = starts[g], s1 = starts[g + 1];
    float sum = 0.f;
    for (int i = s0; i < s1; ++i) sum += bf2f(hbf[(size_t)i * 256 + c]);
    float cnt = (float)(s1 - s0);
    gbf[(size_t)g * 256 + c] = f2bf(sum / fmaxf(cnt, 1.0f));
}

extern "C" void kernel_launch(void* const* d_in, const int* in_sizes, int n_in,
                              void* d_out, int out_size, void* d_ws, size_t ws_size,
                              hipStream_t stream)
{
    const int*   x        = (const int*)d_in[0];
    const int*   ei       = (const int*)d_in[1];
    const int*   eattr    = (const int*)d_in[2];
    const int*   batch    = (const int*)d_in[3];
    const float* node_emb = (const float*)d_in[4];
    const float* edge_emb = (const float*)d_in[5];
    const float* vn_emb   = (const float*)d_in[6];
    const float* eps      = (const float*)d_in[7];
    const float* W1       = (const float*)d_in[8];
    const float* b1       = (const float*)d_in[9];
    const float* W2       = (const float*)d_in[10];
    const float* b2       = (const float*)d_in[11];
    const float* bng      = (const float*)d_in[12];
    const float* bnb      = (const float*)d_in[13];
    const float* bnm      = (const float*)d_in[14];
    const float* bnv      = (const float*)d_in[15];
    const float* vW1      = (const float*)d_in[16];
    const float* vb1      = (const float*)d_in[17];
    const float* vW2      = (const float*)d_in[18];
    const float* vb2      = (const float*)d_in[19];
    const float* hW1      = (const float*)d_in[20];
    const float* hb1      = (const float*)d_in[21];
    const float* hW2      = (const float*)d_in[22];
    const float* hb2      = (const float*)d_in[23];
    float* out = (float*)d_out;

    char* ws = (char*)d_ws;
    size_t off = 0;
    auto alloc = [&](size_t b) {
        char* p = ws + off;
        off = (off + b + 255) & ~(size_t)255;
        return p;
    };
    u16*   hbf  = (u16*)alloc((size_t)NN * 256 * 2);
    u16*   Abf  = (u16*)alloc((size_t)NN * 256 * 2);
    float* vn   = (float*)alloc((size_t)NG * 256 * 4);
    u16*   vnbf = (u16*)alloc((size_t)NG * 256 * 2);
    u16*   gbf  = (u16*)alloc((size_t)NG * 256 * 2);
    u16*   Wt   = (u16*)alloc((size_t)21 * 65536 * 2);
    int*   starts = (int*)alloc((size_t)(NG + 1) * 4);
    u16*   comb = (u16*)alloc((size_t)60 * 256 * 2);
    int*   deg  = (int*)alloc((size_t)NN * 4);
    u32*   slots = (u32*)alloc((size_t)NN * CAP * 4);

    const int* srcI = ei;
    const int* dstI = ei + NE;

    k_prep_weights<<<21 * 256, 256, 0, stream>>>(W1, W2, vW1, vW2, hW1, Wt);
    k_comb<<<60, 256, 0, stream>>>(edge_emb, comb);
    k_starts<<<(NG + 1 + 255) / 256, 256, 0, stream>>>(batch, starts);
    k_vn_init<<<NG, 256, 0, stream>>>(vn_emb, vn, vnbf);
    k_embed<<<NN / 4, 256, 0, stream>>>(x, node_emb, hbf);
    hipMemsetAsync(deg, 0, (size_t)NN * 4, stream);
    k_bucket<<<(NE + 255) / 256, 256, 0, stream>>>(srcI, dstI, eattr, deg, slots);

    const int GBIG = (NN + 63) / 64;   // 938 blocks
    const int GSM  = NG / 64;          // 32 blocks

    for (int l = 0; l < NL; ++l) {
        k_agg<<<NN / 4, 256, 0, stream>>>(hbf, vnbf, batch, slots, deg, comb, Abf, eps + l);
        k_mlp<0><<<GBIG, 512, 0, stream>>>(Abf,
                                           Wt + (size_t)(0 + l) * 65536,
                                           Wt + (size_t)(5 + l) * 65536,
                                           b1 + l * 256, b2 + l * 256, hbf,
                                           bng + l * 256, bnb + l * 256,
                                           bnm + l * 256, bnv + l * 256,
                                           nullptr, nullptr, NN);
        k_pool<<<NG, 256, 0, stream>>>(hbf, starts, gbf);
        k_mlp<1><<<GSM, 512, 0, stream>>>(gbf,
                                          Wt + (size_t)(10 + l) * 65536,
                                          Wt + (size_t)(15 + l) * 65536,
                                          vb1 + l * 256, vb2 + l * 256, nullptr,
                                          nullptr, nullptr, nullptr, nullptr,
                                          vn, vnbf, NG);
    }
    k_pool<<<NG, 256, 0, stream>>>(hbf, starts, gbf);
    k_headf<<<GSM, 512, 0, stream>>>(gbf, Wt + (size_t)20 * 65536, hb1, hW2, hb2, out);
}

// Round 5
// 601.798 us; speedup vs baseline: 6.5176x; 1.0306x over previous
//
#include <hip/hip_runtime.h>

#define NN 60000
#define NE 180000
#define NG 2048
#define NL 5
#define CAP 32

typedef unsigned short u16;
typedef unsigned int u32;
typedef __bf16 bf16x8 __attribute__((ext_vector_type(8)));
typedef float f32x4 __attribute__((ext_vector_type(4)));

__device__ __forceinline__ u16 f2bf(float f) {
    u32 u = __builtin_bit_cast(u32, f);
    u += 0x7FFFu + ((u >> 16) & 1u);
    return (u16)(u >> 16);
}
__device__ __forceinline__ float bf2f(u16 s) {
    return __builtin_bit_cast(float, (u32)s << 16);
}
__device__ __forceinline__ void gload_lds16(const void* g, void* l) {
    __builtin_amdgcn_global_load_lds(
        (const __attribute__((address_space(1))) unsigned int*)g,
        (__attribute__((address_space(3))) unsigned int*)l, 16, 0, 0);
}

__constant__ int NODE_OFF[9]  = {0, 119, 124, 136, 148, 158, 164, 170, 172};
__constant__ int NODE_MAXC[9] = {118, 4, 11, 11, 9, 5, 5, 1, 1};

// ---- transpose + bf16-cast the 21 256x256 weight matrices ----
__global__ __launch_bounds__(256) void k_prep_weights(
    const float* __restrict__ W1, const float* __restrict__ W2,
    const float* __restrict__ vW1, const float* __restrict__ vW2,
    const float* __restrict__ hW1, u16* __restrict__ Wt)
{
    int mat = blockIdx.x >> 8;
    int n = blockIdx.x & 255;
    int k = threadIdx.x;
    const float* src;
    if (mat < 5)       src = W1 + (size_t)mat * 65536;
    else if (mat < 10) src = W2 + (size_t)(mat - 5) * 65536;
    else if (mat < 15) src = vW1 + (size_t)(mat - 10) * 65536;
    else if (mat < 20) src = vW2 + (size_t)(mat - 15) * 65536;
    else               src = hW1;
    Wt[(size_t)mat * 65536 + n * 256 + k] = f2bf(src[k * 256 + n]);
}

// ---- fused setup: vn init + gsum zero | comb table | segment starts ----
__global__ __launch_bounds__(256) void k_misc(
    const float* __restrict__ eemb, const int* __restrict__ batch,
    const float* __restrict__ vn_emb,
    u16* __restrict__ comb, int* __restrict__ starts,
    float* __restrict__ vn, u16* __restrict__ vnbf, float* __restrict__ gsum)
{
    int b = blockIdx.x;
    if (b < 2048) {
        int i = b * 256 + threadIdx.x;
        float v = vn_emb[i & 255];
        vn[i] = v;
        vnbf[i] = f2bf(v);
        gsum[i] = 0.f;
    } else if (b < 2108) {
        int r = b - 2048, c = threadIdx.x;
        int a0 = r / 12, a1 = (r % 12) / 2, a2 = r & 1;
        comb[r * 256 + c] = f2bf(eemb[a0 * 256 + c] + eemb[(5 + a1) * 256 + c] +
                                 eemb[(11 + a2) * 256 + c]);
    } else {
        int g = (b - 2108) * 256 + threadIdx.x;
        if (g > NG) return;
        int lo = 0, hi = NN;
        while (lo < hi) {
            int mid = (lo + hi) >> 1;
            if (batch[mid] < g) lo = mid + 1; else hi = mid;
        }
        starts[g] = lo;
    }
}

// ---- node embedding -> bf16 h; also zero deg ----
__global__ __launch_bounds__(256) void k_embed(const int* __restrict__ x,
                                               const float* __restrict__ node_emb,
                                               u16* __restrict__ hbf,
                                               int* __restrict__ deg)
{
    int i = blockIdx.x * 4 + (threadIdx.x >> 6);
    if (i >= NN) return;
    if ((threadIdx.x & 63) == 0) deg[i] = 0;
    int c = (threadIdx.x & 63) * 4;
    float4 s = make_float4(0.f, 0.f, 0.f, 0.f);
#pragma unroll
    for (int f = 0; f < 9; ++f) {
        int xv = x[i * 9 + f];
        xv = xv < 0 ? 0 : (xv > NODE_MAXC[f] ? NODE_MAXC[f] : xv);
        const float4 t = *(const float4*)&node_emb[(size_t)(NODE_OFF[f] + xv) * 256 + c];
        s.x += t.x; s.y += t.y; s.z += t.z; s.w += t.w;
    }
    ushort4 o;
    o.x = f2bf(s.x); o.y = f2bf(s.y); o.z = f2bf(s.z); o.w = f2bf(s.w);
    *(ushort4*)&hbf[(size_t)i * 256 + c] = o;
}

// ---- CSR-bucket build: slots[d*CAP+p] = src | code<<17 ----
__global__ __launch_bounds__(256) void k_bucket(
    const int* __restrict__ src, const int* __restrict__ dst,
    const int* __restrict__ eattr, int* __restrict__ deg, u32* __restrict__ slots)
{
    int e = blockIdx.x * 256 + threadIdx.x;
    if (e >= NE) return;
    int a0 = eattr[e * 3 + 0]; a0 = a0 < 0 ? 0 : (a0 > 4 ? 4 : a0);
    int a1 = eattr[e * 3 + 1]; a1 = a1 < 0 ? 0 : (a1 > 5 ? 5 : a1);
    int a2 = eattr[e * 3 + 2]; a2 = a2 < 0 ? 0 : (a2 > 1 ? 1 : a2);
    u32 code = (u32)(a0 * 12 + a1 * 2 + a2);
    int d = dst[e];
    int p = atomicAdd(&deg[d], 1);
    if (p < CAP) slots[(size_t)d * CAP + p] = (u32)src[e] | (code << 17);
}

// ======== shared GEMM building blocks (64-row tile, 8 waves of 32x64) ========
// Stage a 256x64 bf16 W panel (pre-transposed [n][k]) into Bl with chunk-XOR swizzle.
__device__ __forceinline__ void stageW(const u16* __restrict__ W, u16* Bl,
                                       int k0, int tid, int wid)
{
#pragma unroll
    for (int i = 0; i < 4; ++i) {
        int slot = i * 512 + tid;
        int row = slot >> 3, cch = slot & 7;
        int g = cch ^ (row & 7);
        gload_lds16((const char*)W + (size_t)row * 512 + (size_t)k0 * 2 + (g << 4),
                    (char*)Bl + ((i * 512 + wid * 64) << 4));
    }
}

// acc += Tl(A, full-K swizzled) @ W.  Barrier-at-top protects prior Bl/Tl use.
__device__ __forceinline__ void gemm64(const u16* Tl, u16* Bl, const u16* __restrict__ W,
                                       f32x4 (&acc)[2][4], int wm, int wn,
                                       int lane, int tid, int wid)
{
    const int cl = lane & 15;
    for (int k0 = 0; k0 < 256; k0 += 64) {
        __syncthreads();
        stageW(W, Bl, k0, tid, wid);
        __syncthreads();
#pragma unroll
        for (int kw = 0; kw < 2; ++kw) {
            int q = kw * 4 + (lane >> 4);
            int qt = (k0 >> 3) + q;
            bf16x8 af[2], bfr[4];
#pragma unroll
            for (int t = 0; t < 2; ++t) {
                int ar = wm + t * 16 + cl;
                af[t] = __builtin_bit_cast(bf16x8,
                    *(const uint4*)((const char*)Tl + (ar << 9) + ((qt ^ (ar & 7)) << 4)));
            }
#pragma unroll
            for (int t = 0; t < 4; ++t) {
                int br = wn + t * 16 + cl;
                bfr[t] = __builtin_bit_cast(bf16x8,
                    *(const uint4*)((const char*)Bl + (br << 7) + ((q ^ (br & 7)) << 4)));
            }
#pragma unroll
            for (int i = 0; i < 2; ++i)
#pragma unroll
                for (int j = 0; j < 4; ++j)
                    acc[i][j] = __builtin_amdgcn_mfma_f32_16x16x32_bf16(af[i], bfr[j], acc[i][j], 0, 0, 0);
        }
    }
}

// T = relu(acc + b1) -> Tl (chunk-XOR swizzled bf16)
__device__ __forceinline__ void writeT(u16* Tl, const f32x4 (&acc)[2][4],
                                       const float* __restrict__ b1,
                                       int wm, int wn, int lane)
{
    const int cl = lane & 15, rg = lane >> 4;
#pragma unroll
    for (int j = 0; j < 4; ++j) {
        int col = wn + j * 16 + cl;
        float bv = b1[col];
#pragma unroll
        for (int i = 0; i < 2; ++i)
#pragma unroll
            for (int r = 0; r < 4; ++r) {
                int row = wm + i * 16 + rg * 4 + r;
                float v = fmaxf(acc[i][j][r] + bv, 0.f);
                *(u16*)((char*)Tl + (row << 9) + ((((col >> 3) ^ (row & 7))) << 4) +
                        ((col & 7) << 1)) = f2bf(v);
            }
    }
}

// ======== fused layer kernel: gather-agg -> MLP -> BN/ReLU -> h' + pooled gsum ========
__global__ __launch_bounds__(512) void k_mlpA(
    const u16* __restrict__ hcur, u16* __restrict__ hnxt,
    const u16* __restrict__ vnbf, const int* __restrict__ batch,
    const u32* __restrict__ slots, const int* __restrict__ deg,
    const u16* __restrict__ comb, const float* __restrict__ epsp,
    const u16* __restrict__ W1t, const u16* __restrict__ W2t,
    const float* __restrict__ b1, const float* __restrict__ b2,
    const float* __restrict__ bng, const float* __restrict__ bnb,
    const float* __restrict__ bnm, const float* __restrict__ bnv,
    float* __restrict__ gsum)
{
    __shared__ __align__(16) u16 Bl[256 * 64];   // 32 KB: W panel
    __shared__ __align__(16) u16 Tl[64 * 256];   // 32 KB: A, then T, then h-stash
    __shared__ int batchLds[64];
    const int m0 = blockIdx.x * 64;
    const int tid = threadIdx.x, lane = tid & 63, wid = tid >> 6;
    const int wm = (wid >> 2) * 32, wn = (wid & 3) * 64;
    const int cl = lane & 15, rg = lane >> 4;

    if (tid < 64) batchLds[tid] = (m0 + tid < NN) ? batch[m0 + tid] : -1;

    // ---- producer: A = (1+eps)*(h+vn) + sum_e relu(h[src]+vn[b]+comb) -> Tl ----
    {
        const float ep = 1.0f + *epsp;
        const int c = lane * 4;
#pragma unroll
        for (int n = 0; n < 8; ++n) {
            int d = m0 + wid * 8 + n;
            ushort4 o = make_ushort4(0, 0, 0, 0);
            if (d < NN) {
                int nd = deg[d]; nd = nd > CAP ? CAP : nd;
                const u32* sl = slots + (size_t)d * CAP;
                u32 sv_l = (lane < nd) ? sl[lane] : 0u;
                int b_l = (lane < nd) ? batch[sv_l & 0x1FFFFu] : 0;
                float4 acc = make_float4(0.f, 0.f, 0.f, 0.f);
                for (int p = 0; p < nd; ++p) {
                    u32 sv = (u32)__shfl((int)sv_l, p);
                    int b  = __shfl(b_l, p);
                    int s  = (int)(sv & 0x1FFFFu);
                    int code = (int)(sv >> 17);
                    const ushort4 hv = *(const ushort4*)&hcur[(size_t)s * 256 + c];
                    const ushort4 vv = *(const ushort4*)&vnbf[(size_t)b * 256 + c];
                    const ushort4 tv = *(const ushort4*)&comb[(size_t)code * 256 + c];
                    acc.x += fmaxf(bf2f(hv.x) + bf2f(vv.x) + bf2f(tv.x), 0.f);
                    acc.y += fmaxf(bf2f(hv.y) + bf2f(vv.y) + bf2f(tv.y), 0.f);
                    acc.z += fmaxf(bf2f(hv.z) + bf2f(vv.z) + bf2f(tv.z), 0.f);
                    acc.w += fmaxf(bf2f(hv.w) + bf2f(vv.w) + bf2f(tv.w), 0.f);
                }
                int bd = batch[d];
                const ushort4 hd = *(const ushort4*)&hcur[(size_t)d * 256 + c];
                const ushort4 vd = *(const ushort4*)&vnbf[(size_t)bd * 256 + c];
                o.x = f2bf((bf2f(hd.x) + bf2f(vd.x)) * ep + acc.x);
                o.y = f2bf((bf2f(hd.y) + bf2f(vd.y)) * ep + acc.y);
                o.z = f2bf((bf2f(hd.z) + bf2f(vd.z)) * ep + acc.z);
                o.w = f2bf((bf2f(hd.w) + bf2f(vd.w)) * ep + acc.w);
            }
            int row = wid * 8 + n;
            *(ushort4*)((char*)Tl + (row << 9) + ((((c >> 3) ^ (row & 7))) << 4) +
                        ((c & 7) << 1)) = o;
        }
    }
    __syncthreads();

    // ---- phase 1: T = relu(A @ W1 + b1) ----
    f32x4 acc1[2][4] = {};
    gemm64(Tl, Bl, W1t, acc1, wm, wn, lane, tid, wid);
    __syncthreads();                       // all Tl(A) reads done
    writeT(Tl, acc1, b1, wm, wn, lane);    // overwrite Tl with T

    // ---- phase 2: Z = T @ W2 + b2 ----
    f32x4 acc2[2][4] = {};
    gemm64(Tl, Bl, W2t, acc2, wm, wn, lane, tid, wid);
    __syncthreads();                       // all Tl(T) reads done

    // ---- epilogue: h' = relu(BN(Z)); write global + stash plain [64][256] ----
#pragma unroll
    for (int j = 0; j < 4; ++j) {
        int gn = wn + j * 16 + cl;
        float bv = b2[gn];
        float sc = bng[gn] * rsqrtf(bnv[gn] + 1e-5f);
        float sh = bnb[gn] - bnm[gn] * sc;
#pragma unroll
        for (int i = 0; i < 2; ++i) {
#pragma unroll
            for (int r = 0; r < 4; ++r) {
                int lr = wm + i * 16 + rg * 4 + r;
                int gm = m0 + lr;
                if (gm >= NN) continue;
                float v = acc2[i][j][r] + bv;
                u16 hb = f2bf(fmaxf(v * sc + sh, 0.f));
                hnxt[(size_t)gm * 256 + gn] = hb;
                Tl[lr * 256 + gn] = hb;
            }
        }
    }
    __syncthreads();

    // ---- pooled partial sums -> gsum atomics (batch sorted => few runs) ----
    {
        int col = tid & 255, half = tid >> 8;
        float s = 0.f;
        int gcur = -1;
        int r0 = half * 32;
        for (int r = r0; r < r0 + 32; ++r) {
            int g = batchLds[r];
            if (g < 0) break;
            if (g != gcur) {
                if (gcur >= 0) atomicAdd(&gsum[(size_t)gcur * 256 + col], s);
                gcur = g; s = 0.f;
            }
            s += bf2f(Tl[r * 256 + col]);
        }
        if (gcur >= 0) atomicAdd(&gsum[(size_t)gcur * 256 + col], s);
    }
}

// ======== fused pool-normalize + vn MLP (32 blocks x 64 graphs) ========
__global__ __launch_bounds__(512) void k_vnmlp(
    float* __restrict__ gsum, const int* __restrict__ starts,
    const u16* __restrict__ W1t, const u16* __restrict__ W2t,
    const float* __restrict__ b1, const float* __restrict__ b2,
    float* __restrict__ vn, u16* __restrict__ vnbf)
{
    __shared__ __align__(16) u16 Bl[256 * 64];
    __shared__ __align__(16) u16 Tl[64 * 256];
    const int m0 = blockIdx.x * 64;
    const int tid = threadIdx.x, lane = tid & 63, wid = tid >> 6;
    const int wm = (wid >> 2) * 32, wn = (wid & 3) * 64;
    const int cl = lane & 15, rg = lane >> 4;

    // producer: A = gsum/cnt -> Tl; zero gsum for next layer
    {
        const int c = lane * 4;
#pragma unroll
        for (int n = 0; n < 8; ++n) {
            int row = wid * 8 + n;
            int g = m0 + row;
            float4 sv = *(const float4*)&gsum[(size_t)g * 256 + c];
            *(float4*)&gsum[(size_t)g * 256 + c] = make_float4(0.f, 0.f, 0.f, 0.f);
            float cnt = (float)(starts[g + 1] - starts[g]);
            float inv = 1.0f / fmaxf(cnt, 1.0f);
            ushort4 o;
            o.x = f2bf(sv.x * inv); o.y = f2bf(sv.y * inv);
            o.z = f2bf(sv.z * inv); o.w = f2bf(sv.w * inv);
            *(ushort4*)((char*)Tl + (row << 9) + ((((c >> 3) ^ (row & 7))) << 4) +
                        ((c & 7) << 1)) = o;
        }
    }
    __syncthreads();

    f32x4 acc1[2][4] = {};
    gemm64(Tl, Bl, W1t, acc1, wm, wn, lane, tid, wid);
    __syncthreads();
    writeT(Tl, acc1, b1, wm, wn, lane);

    f32x4 acc2[2][4] = {};
    gemm64(Tl, Bl, W2t, acc2, wm, wn, lane, tid, wid);

    // epilogue: vn += Z + b2; vnbf = bf16(vn)
#pragma unroll
    for (int j = 0; j < 4; ++j) {
        int gn = wn + j * 16 + cl;
        float bv = b2[gn];
#pragma unroll
        for (int i = 0; i < 2; ++i) {
#pragma unroll
            for (int r = 0; r < 4; ++r) {
                int gm = m0 + wm + i * 16 + rg * 4 + r;
                size_t idx = (size_t)gm * 256 + gn;
                float nv = vn[idx] + acc2[i][j][r] + bv;
                vn[idx] = nv;
                vnbf[idx] = f2bf(nv);
            }
        }
    }
}

// ======== fused head: pool-normalize -> relu(.@hW1+hb1) -> matvec hW2 ========
__global__ __launch_bounds__(512) void k_headf(
    const float* __restrict__ gsum, const int* __restrict__ starts,
    const u16* __restrict__ W1t, const float* __restrict__ b1,
    const float* __restrict__ hW2, const float* __restrict__ hb2,
    float* __restrict__ out)
{
    __shared__ __align__(16) u16 Bl[256 * 64];
    __shared__ __align__(16) u16 Tl[64 * 256];
    const int m0 = blockIdx.x * 64;
    const int tid = threadIdx.x, lane = tid & 63, wid = tid >> 6;
    const int wm = (wid >> 2) * 32, wn = (wid & 3) * 64;

    {
        const int c = lane * 4;
#pragma unroll
        for (int n = 0; n < 8; ++n) {
            int row = wid * 8 + n;
            int g = m0 + row;
            float4 sv = *(const float4*)&gsum[(size_t)g * 256 + c];
            float cnt = (float)(starts[g + 1] - starts[g]);
            float inv = 1.0f / fmaxf(cnt, 1.0f);
            ushort4 o;
            o.x = f2bf(sv.x * inv); o.y = f2bf(sv.y * inv);
            o.z = f2bf(sv.z * inv); o.w = f2bf(sv.w * inv);
            *(ushort4*)((char*)Tl + (row << 9) + ((((c >> 3) ^ (row & 7))) << 4) +
                        ((c & 7) << 1)) = o;
        }
    }
    __syncthreads();

    f32x4 acc1[2][4] = {};
    gemm64(Tl, Bl, W1t, acc1, wm, wn, lane, tid, wid);
    __syncthreads();
    writeT(Tl, acc1, b1, wm, wn, lane);
    __syncthreads();

    // matvec: 8 threads per row
    int row = tid >> 3, oct = tid & 7;
    float s = 0.f;
#pragma unroll
    for (int c = 0; c < 32; ++c) {
        int col = oct * 32 + c;
        int byte = (row << 9) + ((((col >> 3) ^ (row & 7))) << 4) + ((col & 7) << 1);
        s += bf2f(*(const u16*)((const char*)Tl + byte)) * hW2[col];
    }
    s += __shfl_down(s, 4);
    s += __shfl_down(s, 2);
    s += __shfl_down(s, 1);
    if (oct == 0) out[m0 + row] = s + hb2[0];
}

extern "C" void kernel_launch(void* const* d_in, const int* in_sizes, int n_in,
                              void* d_out, int out_size, void* d_ws, size_t ws_size,
                              hipStream_t stream)
{
    const int*   x        = (const int*)d_in[0];
    const int*   ei       = (const int*)d_in[1];
    const int*   eattr    = (const int*)d_in[2];
    const int*   batch    = (const int*)d_in[3];
    const float* node_emb = (const float*)d_in[4];
    const float* edge_emb = (const float*)d_in[5];
    const float* vn_emb   = (const float*)d_in[6];
    const float* eps      = (const float*)d_in[7];
    const float* W1       = (const float*)d_in[8];
    const float* b1       = (const float*)d_in[9];
    const float* W2       = (const float*)d_in[10];
    const float* b2       = (const float*)d_in[11];
    const float* bng      = (const float*)d_in[12];
    const float* bnb      = (const float*)d_in[13];
    const float* bnm      = (const float*)d_in[14];
    const float* bnv      = (const float*)d_in[15];
    const float* vW1      = (const float*)d_in[16];
    const float* vb1      = (const float*)d_in[17];
    const float* vW2      = (const float*)d_in[18];
    const float* vb2      = (const float*)d_in[19];
    const float* hW1      = (const float*)d_in[20];
    const float* hb1      = (const float*)d_in[21];
    const float* hW2      = (const float*)d_in[22];
    const float* hb2      = (const float*)d_in[23];
    float* out = (float*)d_out;

    char* ws = (char*)d_ws;
    size_t off = 0;
    auto alloc = [&](size_t b) {
        char* p = ws + off;
        off = (off + b + 255) & ~(size_t)255;
        return p;
    };
    u16*   hbf0 = (u16*)alloc((size_t)NN * 256 * 2);
    u16*   hbf1 = (u16*)alloc((size_t)NN * 256 * 2);
    float* vn   = (float*)alloc((size_t)NG * 256 * 4);
    u16*   vnbf = (u16*)alloc((size_t)NG * 256 * 2);
    float* gsum = (float*)alloc((size_t)NG * 256 * 4);
    u16*   Wt   = (u16*)alloc((size_t)21 * 65536 * 2);
    int*   starts = (int*)alloc((size_t)(NG + 1) * 4);
    u16*   comb = (u16*)alloc((size_t)60 * 256 * 2);
    int*   deg  = (int*)alloc((size_t)NN * 4);
    u32*   slots = (u32*)alloc((size_t)NN * CAP * 4);

    const int* srcI = ei;
    const int* dstI = ei + NE;

    k_prep_weights<<<21 * 256, 256, 0, stream>>>(W1, W2, vW1, vW2, hW1, Wt);
    k_misc<<<2117, 256, 0, stream>>>(edge_emb, batch, vn_emb, comb, starts, vn, vnbf, gsum);
    k_embed<<<NN / 4, 256, 0, stream>>>(x, node_emb, hbf0, deg);
    k_bucket<<<(NE + 255) / 256, 256, 0, stream>>>(srcI, dstI, eattr, deg, slots);

    const int GBIG = (NN + 63) / 64;   // 938 blocks
    const int GSM  = NG / 64;          // 32 blocks

    u16* hcur = hbf0;
    u16* hnxt = hbf1;
    for (int l = 0; l < NL; ++l) {
        k_mlpA<<<GBIG, 512, 0, stream>>>(hcur, hnxt, vnbf, batch, slots, deg, comb,
                                         eps + l,
                                         Wt + (size_t)(0 + l) * 65536,
                                         Wt + (size_t)(5 + l) * 65536,
                                         b1 + l * 256, b2 + l * 256,
                                         bng + l * 256, bnb + l * 256,
                                         bnm + l * 256, bnv + l * 256,
                                         gsum);
        if (l < NL - 1) {
            k_vnmlp<<<GSM, 512, 0, stream>>>(gsum, starts,
                                             Wt + (size_t)(10 + l) * 65536,
                                             Wt + (size_t)(15 + l) * 65536,
                                             vb1 + l * 256, vb2 + l * 256,
                                             vn, vnbf);
        }
        u16* t = hcur; hcur = hnxt; hnxt = t;
    }
    k_headf<<<GSM, 512, 0, stream>>>(gsum, starts, Wt + (size_t)20 * 65536,
                                     hb1, hW2, hb2, out);
}

// Round 6
// 549.151 us; speedup vs baseline: 7.1425x; 1.0959x over previous
//
#include <hip/hip_runtime.h>

#define NN 60000
#define NE 180000
#define NG 2048
#define NL 5
#define CAP 32

typedef unsigned short u16;
typedef unsigned int u32;
typedef __bf16 bf16x8 __attribute__((ext_vector_type(8)));
typedef float f32x4 __attribute__((ext_vector_type(4)));

__device__ __forceinline__ u16 f2bf(float f) {
    u32 u = __builtin_bit_cast(u32, f);
    u += 0x7FFFu + ((u >> 16) & 1u);
    return (u16)(u >> 16);
}
__device__ __forceinline__ float bf2f(u16 s) {
    return __builtin_bit_cast(float, (u32)s << 16);
}
__device__ __forceinline__ void gload_lds16(const void* g, void* l) {
    __builtin_amdgcn_global_load_lds(
        (const __attribute__((address_space(1))) unsigned int*)g,
        (__attribute__((address_space(3))) unsigned int*)l, 16, 0, 0);
}
// swizzled byte offset into a [rows][256] bf16 LDS tile (chunk ^= row&7)
__device__ __forceinline__ int swz(int row, int col) {
    return (row << 9) + ((((col >> 3) ^ (row & 7))) << 4) + ((col & 7) << 1);
}

__constant__ int NODE_OFF[9]  = {0, 119, 124, 136, 148, 158, 164, 170, 172};
__constant__ int NODE_MAXC[9] = {118, 4, 11, 11, 9, 5, 5, 1, 1};

// ---- transpose + bf16-cast the 21 256x256 weight matrices ----
__global__ __launch_bounds__(256) void k_prep_weights(
    const float* __restrict__ W1, const float* __restrict__ W2,
    const float* __restrict__ vW1, const float* __restrict__ vW2,
    const float* __restrict__ hW1, u16* __restrict__ Wt)
{
    int mat = blockIdx.x >> 8;
    int n = blockIdx.x & 255;
    int k = threadIdx.x;
    const float* src;
    if (mat < 5)       src = W1 + (size_t)mat * 65536;
    else if (mat < 10) src = W2 + (size_t)(mat - 5) * 65536;
    else if (mat < 15) src = vW1 + (size_t)(mat - 10) * 65536;
    else if (mat < 20) src = vW2 + (size_t)(mat - 15) * 65536;
    else               src = hW1;
    Wt[(size_t)mat * 65536 + n * 256 + k] = f2bf(src[k * 256 + n]);
}

// ---- fused setup: vn init + gsum zero | comb table | segment starts ----
__global__ __launch_bounds__(256) void k_misc(
    const float* __restrict__ eemb, const int* __restrict__ batch,
    const float* __restrict__ vn_emb,
    u16* __restrict__ comb, int* __restrict__ starts,
    float* __restrict__ vn, u16* __restrict__ vnbf, float* __restrict__ gsum)
{
    int b = blockIdx.x;
    if (b < 2048) {
        int i = b * 256 + threadIdx.x;
        float v = vn_emb[i & 255];
        vn[i] = v;
        vnbf[i] = f2bf(v);
        gsum[i] = 0.f;
    } else if (b < 2108) {
        int r = b - 2048, c = threadIdx.x;
        int a0 = r / 12, a1 = (r % 12) / 2, a2 = r & 1;
        comb[r * 256 + c] = f2bf(eemb[a0 * 256 + c] + eemb[(5 + a1) * 256 + c] +
                                 eemb[(11 + a2) * 256 + c]);
    } else {
        int g = (b - 2108) * 256 + threadIdx.x;
        if (g > NG) return;
        int lo = 0, hi = NN;
        while (lo < hi) {
            int mid = (lo + hi) >> 1;
            if (batch[mid] < g) lo = mid + 1; else hi = mid;
        }
        starts[g] = lo;
    }
}

// ---- node embedding -> bf16 h; also zero deg ----
__global__ __launch_bounds__(256) void k_embed(const int* __restrict__ x,
                                               const float* __restrict__ node_emb,
                                               u16* __restrict__ hbf,
                                               int* __restrict__ deg)
{
    int i = blockIdx.x * 4 + (threadIdx.x >> 6);
    if (i >= NN) return;
    if ((threadIdx.x & 63) == 0) deg[i] = 0;
    int c = (threadIdx.x & 63) * 4;
    float4 s = make_float4(0.f, 0.f, 0.f, 0.f);
#pragma unroll
    for (int f = 0; f < 9; ++f) {
        int xv = x[i * 9 + f];
        xv = xv < 0 ? 0 : (xv > NODE_MAXC[f] ? NODE_MAXC[f] : xv);
        const float4 t = *(const float4*)&node_emb[(size_t)(NODE_OFF[f] + xv) * 256 + c];
        s.x += t.x; s.y += t.y; s.z += t.z; s.w += t.w;
    }
    ushort4 o;
    o.x = f2bf(s.x); o.y = f2bf(s.y); o.z = f2bf(s.z); o.w = f2bf(s.w);
    *(ushort4*)&hbf[(size_t)i * 256 + c] = o;
}

// ---- CSR-bucket build: slots[d*CAP+p] = src | code<<17 ----
__global__ __launch_bounds__(256) void k_bucket(
    const int* __restrict__ src, const int* __restrict__ dst,
    const int* __restrict__ eattr, int* __restrict__ deg, u32* __restrict__ slots)
{
    int e = blockIdx.x * 256 + threadIdx.x;
    if (e >= NE) return;
    int a0 = eattr[e * 3 + 0]; a0 = a0 < 0 ? 0 : (a0 > 4 ? 4 : a0);
    int a1 = eattr[e * 3 + 1]; a1 = a1 < 0 ? 0 : (a1 > 5 ? 5 : a1);
    int a2 = eattr[e * 3 + 2]; a2 = a2 < 0 ? 0 : (a2 > 1 ? 1 : a2);
    u32 code = (u32)(a0 * 12 + a1 * 2 + a2);
    int d = dst[e];
    int p = atomicAdd(&deg[d], 1);
    if (p < CAP) slots[(size_t)d * CAP + p] = (u32)src[e] | (code << 17);
}

// ---- standalone gather-aggregate: one node per wave, max TLP ----
__global__ __launch_bounds__(256) void k_agg(
    const u16* __restrict__ hbf, const u16* __restrict__ vnbf,
    const int* __restrict__ batch, const u32* __restrict__ slots,
    const int* __restrict__ deg, const u16* __restrict__ comb,
    u16* __restrict__ Abf, const float* __restrict__ epsp)
{
    int d = blockIdx.x * 4 + (threadIdx.x >> 6);
    int lane = threadIdx.x & 63;
    int c = lane * 4;
    int nd = deg[d];
    nd = nd > CAP ? CAP : nd;

    const u32* sl = slots + (size_t)d * CAP;
    u32 sv_l = (lane < nd) ? sl[lane] : 0u;
    int b_l = (lane < nd) ? batch[sv_l & 0x1FFFFu] : 0;

    float4 acc = make_float4(0.f, 0.f, 0.f, 0.f);
    for (int p = 0; p < nd; ++p) {
        u32 sv = (u32)__shfl((int)sv_l, p);
        int b  = __shfl(b_l, p);
        int s  = (int)(sv & 0x1FFFFu);
        int code = (int)(sv >> 17);
        const ushort4 hv = *(const ushort4*)&hbf[(size_t)s * 256 + c];
        const ushort4 vv = *(const ushort4*)&vnbf[(size_t)b * 256 + c];
        const ushort4 tv = *(const ushort4*)&comb[(size_t)code * 256 + c];
        acc.x += fmaxf(bf2f(hv.x) + bf2f(vv.x) + bf2f(tv.x), 0.f);
        acc.y += fmaxf(bf2f(hv.y) + bf2f(vv.y) + bf2f(tv.y), 0.f);
        acc.z += fmaxf(bf2f(hv.z) + bf2f(vv.z) + bf2f(tv.z), 0.f);
        acc.w += fmaxf(bf2f(hv.w) + bf2f(vv.w) + bf2f(tv.w), 0.f);
    }

    int bd = batch[d];
    float ep = 1.0f + *epsp;
    const ushort4 hd = *(const ushort4*)&hbf[(size_t)d * 256 + c];
    const ushort4 vd = *(const ushort4*)&vnbf[(size_t)bd * 256 + c];
    ushort4 o;
    o.x = f2bf((bf2f(hd.x) + bf2f(vd.x)) * ep + acc.x);
    o.y = f2bf((bf2f(hd.y) + bf2f(vd.y)) * ep + acc.y);
    o.z = f2bf((bf2f(hd.z) + bf2f(vd.z)) * ep + acc.z);
    o.w = f2bf((bf2f(hd.w) + bf2f(vd.w)) * ep + acc.w);
    *(ushort4*)&Abf[(size_t)d * 256 + c] = o;
}

// ======== shared GEMM building blocks (64-row tile, 8 waves of 32x64) ========
__device__ __forceinline__ void stageW(const u16* __restrict__ W, u16* Bl,
                                       int k0, int tid, int wid)
{
#pragma unroll
    for (int i = 0; i < 4; ++i) {
        int slot = i * 512 + tid;
        int row = slot >> 3, cch = slot & 7;
        int g = cch ^ (row & 7);
        gload_lds16((const char*)W + (size_t)row * 512 + (size_t)k0 * 2 + (g << 4),
                    (char*)Bl + ((i * 512 + wid * 64) << 4));
    }
}

// acc += Tl(A, full-K swizzled) @ W.  Barrier-at-top protects prior Bl/Tl use.
__device__ __forceinline__ void gemm64(const u16* Tl, u16* Bl, const u16* __restrict__ W,
                                       f32x4 (&acc)[2][4], int wm, int wn,
                                       int lane, int tid, int wid)
{
    const int cl = lane & 15;
    for (int k0 = 0; k0 < 256; k0 += 64) {
        __syncthreads();
        stageW(W, Bl, k0, tid, wid);
        __syncthreads();
#pragma unroll
        for (int kw = 0; kw < 2; ++kw) {
            int q = kw * 4 + (lane >> 4);
            int qt = (k0 >> 3) + q;
            bf16x8 af[2], bfr[4];
#pragma unroll
            for (int t = 0; t < 2; ++t) {
                int ar = wm + t * 16 + cl;
                af[t] = __builtin_bit_cast(bf16x8,
                    *(const uint4*)((const char*)Tl + (ar << 9) + ((qt ^ (ar & 7)) << 4)));
            }
#pragma unroll
            for (int t = 0; t < 4; ++t) {
                int br = wn + t * 16 + cl;
                bfr[t] = __builtin_bit_cast(bf16x8,
                    *(const uint4*)((const char*)Bl + (br << 7) + ((q ^ (br & 7)) << 4)));
            }
#pragma unroll
            for (int i = 0; i < 2; ++i)
#pragma unroll
                for (int j = 0; j < 4; ++j)
                    acc[i][j] = __builtin_amdgcn_mfma_f32_16x16x32_bf16(af[i], bfr[j], acc[i][j], 0, 0, 0);
        }
    }
}

// T = relu(acc + b1) -> Tl (chunk-XOR swizzled bf16)
__device__ __forceinline__ void writeT(u16* Tl, const f32x4 (&acc)[2][4],
                                       const float* __restrict__ b1,
                                       int wm, int wn, int lane)
{
    const int cl = lane & 15, rg = lane >> 4;
#pragma unroll
    for (int j = 0; j < 4; ++j) {
        int col = wn + j * 16 + cl;
        float bv = b1[col];
#pragma unroll
        for (int i = 0; i < 2; ++i)
#pragma unroll
            for (int r = 0; r < 4; ++r) {
                int row = wm + i * 16 + rg * 4 + r;
                float v = fmaxf(acc[i][j][r] + bv, 0.f);
                *(u16*)((char*)Tl + swz(row, col)) = f2bf(v);
            }
    }
}

// ======== MLP + BN/ReLU + pooled-gsum kernel (A from global Abf) ========
__global__ __launch_bounds__(512) void k_mlpP(
    const u16* __restrict__ Abf, u16* __restrict__ hnxt,
    const int* __restrict__ batch,
    const u16* __restrict__ W1t, const u16* __restrict__ W2t,
    const float* __restrict__ b1, const float* __restrict__ b2,
    const float* __restrict__ bng, const float* __restrict__ bnb,
    const float* __restrict__ bnm, const float* __restrict__ bnv,
    float* __restrict__ gsum)
{
    __shared__ __align__(16) u16 Bl[256 * 64];   // 32 KB: W panel
    __shared__ __align__(16) u16 Tl[64 * 256];   // 32 KB: A -> T -> h stash
    __shared__ int batchLds[64];
    const int m0 = blockIdx.x * 64;
    const int tid = threadIdx.x, lane = tid & 63, wid = tid >> 6;
    const int wm = (wid >> 2) * 32, wn = (wid & 3) * 64;
    const int cl = lane & 15, rg = lane >> 4;

    if (tid < 64) batchLds[tid] = (m0 + tid < NN) ? batch[m0 + tid] : -1;

    // stage A[64 rows] into Tl (full-K, swizzled): 2048 slots, 4 rounds
#pragma unroll
    for (int i = 0; i < 4; ++i) {
        int slot = i * 512 + tid;
        int row = slot >> 5, cch = slot & 31;
        int g = cch ^ (row & 7);
        gload_lds16((const char*)Abf + (size_t)(m0 + row) * 512 + (g << 4),
                    (char*)Tl + ((i * 512 + wid * 64) << 4));
    }
    // (first __syncthreads inside gemm64 drains vmcnt before any Tl read)

    // phase 1: T = relu(A @ W1 + b1)
    f32x4 acc1[2][4] = {};
    gemm64(Tl, Bl, W1t, acc1, wm, wn, lane, tid, wid);
    __syncthreads();
    writeT(Tl, acc1, b1, wm, wn, lane);

    // phase 2: Z = T @ W2 + b2
    f32x4 acc2[2][4] = {};
    gemm64(Tl, Bl, W2t, acc2, wm, wn, lane, tid, wid);
    __syncthreads();

    // epilogue: h' = relu(BN(Z)); write global + swizzled stash
#pragma unroll
    for (int j = 0; j < 4; ++j) {
        int gn = wn + j * 16 + cl;
        float bv = b2[gn];
        float sc = bng[gn] * rsqrtf(bnv[gn] + 1e-5f);
        float sh = bnb[gn] - bnm[gn] * sc;
#pragma unroll
        for (int i = 0; i < 2; ++i) {
#pragma unroll
            for (int r = 0; r < 4; ++r) {
                int lr = wm + i * 16 + rg * 4 + r;
                int gm = m0 + lr;
                if (gm >= NN) continue;
                float v = acc2[i][j][r] + bv;
                u16 hb = f2bf(fmaxf(v * sc + sh, 0.f));
                hnxt[(size_t)gm * 256 + gn] = hb;
                *(u16*)((char*)Tl + swz(lr, gn)) = hb;
            }
        }
    }
    __syncthreads();

    // pooled partial sums -> gsum atomics (batch sorted => few runs)
    {
        int col = tid & 255, half = tid >> 8;
        float s = 0.f;
        int gcur = -1;
        int r0 = half * 32;
        for (int r = r0; r < r0 + 32; ++r) {
            int g = batchLds[r];
            if (g < 0) break;
            if (g != gcur) {
                if (gcur >= 0) atomicAdd(&gsum[(size_t)gcur * 256 + col], s);
                gcur = g; s = 0.f;
            }
            s += bf2f(*(const u16*)((const char*)Tl + swz(r, col)));
        }
        if (gcur >= 0) atomicAdd(&gsum[(size_t)gcur * 256 + col], s);
    }
}

// ======== fused pool-normalize + vn MLP (32 blocks x 64 graphs) ========
__global__ __launch_bounds__(512) void k_vnmlp(
    float* __restrict__ gsum, const int* __restrict__ starts,
    const u16* __restrict__ W1t, const u16* __restrict__ W2t,
    const float* __restrict__ b1, const float* __restrict__ b2,
    float* __restrict__ vn, u16* __restrict__ vnbf)
{
    __shared__ __align__(16) u16 Bl[256 * 64];
    __shared__ __align__(16) u16 Tl[64 * 256];
    const int m0 = blockIdx.x * 64;
    const int tid = threadIdx.x, lane = tid & 63, wid = tid >> 6;
    const int wm = (wid >> 2) * 32, wn = (wid & 3) * 64;
    const int cl = lane & 15, rg = lane >> 4;

    // producer: A = gsum/cnt -> Tl; zero gsum for next layer
    {
        const int c = lane * 4;
#pragma unroll
        for (int n = 0; n < 8; ++n) {
            int row = wid * 8 + n;
            int g = m0 + row;
            float4 sv = *(const float4*)&gsum[(size_t)g * 256 + c];
            *(float4*)&gsum[(size_t)g * 256 + c] = make_float4(0.f, 0.f, 0.f, 0.f);
            float cnt = (float)(starts[g + 1] - starts[g]);
            float inv = 1.0f / fmaxf(cnt, 1.0f);
            ushort4 o;
            o.x = f2bf(sv.x * inv); o.y = f2bf(sv.y * inv);
            o.z = f2bf(sv.z * inv); o.w = f2bf(sv.w * inv);
            *(ushort4*)((char*)Tl + swz(row, c)) = o;
        }
    }
    __syncthreads();

    f32x4 acc1[2][4] = {};
    gemm64(Tl, Bl, W1t, acc1, wm, wn, lane, tid, wid);
    __syncthreads();
    writeT(Tl, acc1, b1, wm, wn, lane);

    f32x4 acc2[2][4] = {};
    gemm64(Tl, Bl, W2t, acc2, wm, wn, lane, tid, wid);

    // epilogue: vn += Z + b2; vnbf = bf16(vn)
#pragma unroll
    for (int j = 0; j < 4; ++j) {
        int gn = wn + j * 16 + cl;
        float bv = b2[gn];
#pragma unroll
        for (int i = 0; i < 2; ++i) {
#pragma unroll
            for (int r = 0; r < 4; ++r) {
                int gm = m0 + wm + i * 16 + rg * 4 + r;
                size_t idx = (size_t)gm * 256 + gn;
                float nv = vn[idx] + acc2[i][j][r] + bv;
                vn[idx] = nv;
                vnbf[idx] = f2bf(nv);
            }
        }
    }
}

// ======== fused head: pool-normalize -> relu(.@hW1+hb1) -> matvec hW2 ========
__global__ __launch_bounds__(512) void k_headf(
    const float* __restrict__ gsum, const int* __restrict__ starts,
    const u16* __restrict__ W1t, const float* __restrict__ b1,
    const float* __restrict__ hW2, const float* __restrict__ hb2,
    float* __restrict__ out)
{
    __shared__ __align__(16) u16 Bl[256 * 64];
    __shared__ __align__(16) u16 Tl[64 * 256];
    const int m0 = blockIdx.x * 64;
    const int tid = threadIdx.x, lane = tid & 63, wid = tid >> 6;
    const int wm = (wid >> 2) * 32, wn = (wid & 3) * 64;

    {
        const int c = lane * 4;
#pragma unroll
        for (int n = 0; n < 8; ++n) {
            int row = wid * 8 + n;
            int g = m0 + row;
            float4 sv = *(const float4*)&gsum[(size_t)g * 256 + c];
            float cnt = (float)(starts[g + 1] - starts[g]);
            float inv = 1.0f / fmaxf(cnt, 1.0f);
            ushort4 o;
            o.x = f2bf(sv.x * inv); o.y = f2bf(sv.y * inv);
            o.z = f2bf(sv.z * inv); o.w = f2bf(sv.w * inv);
            *(ushort4*)((char*)Tl + swz(row, c)) = o;
        }
    }
    __syncthreads();

    f32x4 acc1[2][4] = {};
    gemm64(Tl, Bl, W1t, acc1, wm, wn, lane, tid, wid);
    __syncthreads();
    writeT(Tl, acc1, b1, wm, wn, lane);
    __syncthreads();

    // matvec: 8 threads per row
    int row = tid >> 3, oct = tid & 7;
    float s = 0.f;
#pragma unroll
    for (int c = 0; c < 32; ++c) {
        int col = oct * 32 + c;
        s += bf2f(*(const u16*)((const char*)Tl + swz(row, col))) * hW2[col];
    }
    s += __shfl_down(s, 4);
    s += __shfl_down(s, 2);
    s += __shfl_down(s, 1);
    if (oct == 0) out[m0 + row] = s + hb2[0];
}

extern "C" void kernel_launch(void* const* d_in, const int* in_sizes, int n_in,
                              void* d_out, int out_size, void* d_ws, size_t ws_size,
                              hipStream_t stream)
{
    const int*   x        = (const int*)d_in[0];
    const int*   ei       = (const int*)d_in[1];
    const int*   eattr    = (const int*)d_in[2];
    const int*   batch    = (const int*)d_in[3];
    const float* node_emb = (const float*)d_in[4];
    const float* edge_emb = (const float*)d_in[5];
    const float* vn_emb   = (const float*)d_in[6];
    const float* eps      = (const float*)d_in[7];
    const float* W1       = (const float*)d_in[8];
    const float* b1       = (const float*)d_in[9];
    const float* W2       = (const float*)d_in[10];
    const float* b2       = (const float*)d_in[11];
    const float* bng      = (const float*)d_in[12];
    const float* bnb      = (const float*)d_in[13];
    const float* bnm      = (const float*)d_in[14];
    const float* bnv      = (const float*)d_in[15];
    const float* vW1      = (const float*)d_in[16];
    const float* vb1      = (const float*)d_in[17];
    const float* vW2      = (const float*)d_in[18];
    const float* vb2      = (const float*)d_in[19];
    const float* hW1      = (const float*)d_in[20];
    const float* hb1      = (const float*)d_in[21];
    const float* hW2      = (const float*)d_in[22];
    const float* hb2      = (const float*)d_in[23];
    float* out = (float*)d_out;

    char* ws = (char*)d_ws;
    size_t off = 0;
    auto alloc = [&](size_t b) {
        char* p = ws + off;
        off = (off + b + 255) & ~(size_t)255;
        return p;
    };
    u16*   hbf0 = (u16*)alloc((size_t)NN * 256 * 2);
    u16*   hbf1 = (u16*)alloc((size_t)NN * 256 * 2);
    u16*   Abf  = (u16*)alloc((size_t)NN * 256 * 2);
    float* vn   = (float*)alloc((size_t)NG * 256 * 4);
    u16*   vnbf = (u16*)alloc((size_t)NG * 256 * 2);
    float* gsum = (float*)alloc((size_t)NG * 256 * 4);
    u16*   Wt   = (u16*)alloc((size_t)21 * 65536 * 2);
    int*   starts = (int*)alloc((size_t)(NG + 1) * 4);
    u16*   comb = (u16*)alloc((size_t)60 * 256 * 2);
    int*   deg  = (int*)alloc((size_t)NN * 4);
    u32*   slots = (u32*)alloc((size_t)NN * CAP * 4);

    const int* srcI = ei;
    const int* dstI = ei + NE;

    k_prep_weights<<<21 * 256, 256, 0, stream>>>(W1, W2, vW1, vW2, hW1, Wt);
    k_misc<<<2117, 256, 0, stream>>>(edge_emb, batch, vn_emb, comb, starts, vn, vnbf, gsum);
    k_embed<<<NN / 4, 256, 0, stream>>>(x, node_emb, hbf0, deg);
    k_bucket<<<(NE + 255) / 256, 256, 0, stream>>>(srcI, dstI, eattr, deg, slots);

    const int GBIG = (NN + 63) / 64;   // 938 blocks
    const int GSM  = NG / 64;          // 32 blocks

    u16* hcur = hbf0;
    u16* hnxt = hbf1;
    for (int l = 0; l < NL; ++l) {
        k_agg<<<NN / 4, 256, 0, stream>>>(hcur, vnbf, batch, slots, deg, comb, Abf, eps + l);
        k_mlpP<<<GBIG, 512, 0, stream>>>(Abf, hnxt, batch,
                                         Wt + (size_t)(0 + l) * 65536,
                                         Wt + (size_t)(5 + l) * 65536,
                                         b1 + l * 256, b2 + l * 256,
                                         bng + l * 256, bnb + l * 256,
                                         bnm + l * 256, bnv + l * 256,
                                         gsum);
        if (l < NL - 1) {
            k_vnmlp<<<GSM, 512, 0, stream>>>(gsum, starts,
                                             Wt + (size_t)(10 + l) * 65536,
                                             Wt + (size_t)(15 + l) * 65536,
                                             vb1 + l * 256, vb2 + l * 256,
                                             vn, vnbf);
        }
        u16* t = hcur; hcur = hnxt; hnxt = t;
    }
    k_headf<<<GSM, 512, 0, stream>>>(gsum, starts, Wt + (size_t)20 * 65536,
                                     hb1, hW2, hb2, out);
}